// Round 1
// baseline (6194.954 us; speedup 1.0000x reference)
//
#include <hip/hip_runtime.h>
#include <math.h>

// Problem constants
#define SEQL 128
#define NB   32
#define EMBD 300
#define HH   400      // hidden per direction
#define G4   1600     // 4*HH
#define FF   512
#define NLAB 9
#define NBLK 200      // persistent LSTM blocks: 2 dirs x 100 slices (4 hidden units each)

// ---------------- workspace layout (bytes) ----------------
static const size_t OFF_X    = 0;          // x [4096][300] f32 — dead after input GEMMs
static const size_t OFF_HBUF = 0;          // h double-buffer [2][2][400][32] f64 (819,200) — live only in k_lstm3
static const size_t OFF_FLG  = 1048576;    // publish flags [2][128] u32 — in dead x region
static const size_t OFF_XW   = 5242880;    // XWt [2][128][32][1600] f32 (52,428,800) dead after LSTM; he reuses it
static const size_t OFF_HE   = 5242880;    // he [4096][512] f32 (8,388,608) — after LSTM, before gemm_nn
static const size_t OFF_ENC  = 62914560;   // enc [4096][800] f32 (13,107,200) dead after proj GEMMs
static const size_t OFF_U    = 0;          // U [4096][9][516] f32 (76,087,296) overlays all of the above post-proj
static const size_t OFF_X1   = 76087296;   // x1 [4096][516] (8,454,144)
static const size_t OFF_Y1T  = 84541440;   // y1T [32][513][128] (8,404,992)
static const size_t OFF_KEYS = 92946432;   // keys u64 [32][16384] (4,194,304)
static const size_t OFF_WBP  = 97140736;   // Wb padded [9][513][516] (9,529,488)

// ---------------- agent-scope (IF-coherent, cache-bypassing) accessors ----------------
__device__ __forceinline__ double aload(const double* p) {
  return __hip_atomic_load(p, __ATOMIC_RELAXED, __HIP_MEMORY_SCOPE_AGENT);
}
__device__ __forceinline__ void astore(double* p, double v) {
  __hip_atomic_store(p, v, __ATOMIC_RELAXED, __HIP_MEMORY_SCOPE_AGENT);
}
__device__ __forceinline__ unsigned afload(const unsigned* p) {
  return __hip_atomic_load(p, __ATOMIC_RELAXED, __HIP_MEMORY_SCOPE_AGENT);
}
__device__ __forceinline__ void afstore(unsigned* p, unsigned v) {
  __hip_atomic_store(p, v, __ATOMIC_RELAXED, __HIP_MEMORY_SCOPE_AGENT);
}

// ---------------- embedding gather ----------------
__global__ __launch_bounds__(256) void k_gather(const int* __restrict__ wi,
                                                const float* __restrict__ emb,
                                                float* __restrict__ x) {
  int m = blockIdx.x;
  int idx = wi[m];
  const float* src = emb + (size_t)idx * EMBD;
  float* dst = x + (size_t)m * EMBD;
  for (int e = threadIdx.x; e < EMBD; e += 256) dst[e] = src[e];
}

// ---------------- W_biaffine pad to stride 516 ----------------
__global__ __launch_bounds__(256) void k_wbpad(const float* __restrict__ wbi,
                                               float* __restrict__ wbp) {
  int tid = blockIdx.x * 256 + threadIdx.x;
  const int PER = 513 * 516;
  if (tid >= 9 * PER) return;
  int o = tid / PER;
  int r = tid - o * PER;
  int i = r / 516;
  int j = r - i * 516;
  wbp[tid] = (j < 513) ? wbi[(size_t)o * 513 * 513 + (size_t)i * 513 + j] : 0.f;
}

// ---------------- ones columns ----------------
__global__ __launch_bounds__(256) void k_ones(float* __restrict__ x1, float* __restrict__ y1T) {
  int tid = blockIdx.x * 256 + threadIdx.x;
  if (tid < 4096) {
    x1[(size_t)tid * 516 + 512] = 1.f;
  } else if (tid < 8192) {
    int r = tid - 4096;
    int bb = r >> 7, y = r & 127;
    y1T[((size_t)bb * 513 + 512) * 128 + y] = 1.f;
  }
}

// ---------------- he -> y1T transpose (coalesced both sides) ----------------
__global__ __launch_bounds__(256) void k_y1t(const float* __restrict__ he,
                                             float* __restrict__ y1T) {
  __shared__ float tile[32][33];
  int b = blockIdx.z;
  int n0 = blockIdx.x * 32, y0 = blockIdx.y * 32;
  int tx = threadIdx.x & 31, ty = threadIdx.x >> 5;
  for (int yy = ty; yy < 32; yy += 8)
    tile[yy][tx] = he[((size_t)b * 128 + y0 + yy) * 512 + n0 + tx];
  __syncthreads();
  for (int nn = ty; nn < 32; nn += 8)
    y1T[((size_t)b * 513 + n0 + nn) * 128 + y0 + tx] = tile[tx][nn];
}

// ---------------- tiled GEMM, f64 accumulate, C = A * W^T (+b1+b2)
// mode 0: normal store (ldc); mode 2: XWt store [l][b][n] (coalesced)
__global__ __launch_bounds__(256) void k_gemm_nt(const float* __restrict__ A, int lda,
                                                 const float* __restrict__ W, int ldw,
                                                 const float* __restrict__ bias1,
                                                 const float* __restrict__ bias2,
                                                 float* __restrict__ C, int ldc,
                                                 int M, int N, int K, int mode) {
  __shared__ __align__(16) double As[16][68];
  __shared__ __align__(16) double Bs[16][68];
  int t = threadIdx.x;
  int m0 = blockIdx.x * 64, n0 = blockIdx.y * 64;
  int tm = t & 15, tn = t >> 4;
  int ar = t >> 2, akq = t & 3;
  double acc[4][4];
#pragma unroll
  for (int r = 0; r < 4; ++r)
#pragma unroll
    for (int c = 0; c < 4; ++c) acc[r][c] = 0.0;

  for (int k0 = 0; k0 < K; k0 += 16) {
    {
      const float* ap = A + (size_t)(m0 + ar) * lda + k0 + 4 * akq;
      float v0, v1, v2, v3;
      if (k0 + 4 * akq + 4 <= K) {
        float4 f = *(const float4*)ap; v0 = f.x; v1 = f.y; v2 = f.z; v3 = f.w;
      } else {
        v0 = (k0 + 4 * akq + 0 < K) ? ap[0] : 0.f;
        v1 = (k0 + 4 * akq + 1 < K) ? ap[1] : 0.f;
        v2 = (k0 + 4 * akq + 2 < K) ? ap[2] : 0.f;
        v3 = (k0 + 4 * akq + 3 < K) ? ap[3] : 0.f;
      }
      As[4 * akq + 0][ar] = (double)v0; As[4 * akq + 1][ar] = (double)v1;
      As[4 * akq + 2][ar] = (double)v2; As[4 * akq + 3][ar] = (double)v3;
    }
    {
      int nr = n0 + ar;
      float v0 = 0.f, v1 = 0.f, v2 = 0.f, v3 = 0.f;
      if (nr < N) {
        const float* wp = W + (size_t)nr * ldw + k0 + 4 * akq;
        if (k0 + 4 * akq + 4 <= K) {
          float4 f = *(const float4*)wp; v0 = f.x; v1 = f.y; v2 = f.z; v3 = f.w;
        } else {
          if (k0 + 4 * akq + 0 < K) v0 = wp[0];
          if (k0 + 4 * akq + 1 < K) v1 = wp[1];
          if (k0 + 4 * akq + 2 < K) v2 = wp[2];
          if (k0 + 4 * akq + 3 < K) v3 = wp[3];
        }
      }
      Bs[4 * akq + 0][ar] = (double)v0; Bs[4 * akq + 1][ar] = (double)v1;
      Bs[4 * akq + 2][ar] = (double)v2; Bs[4 * akq + 3][ar] = (double)v3;
    }
    __syncthreads();
#pragma unroll
    for (int kk = 0; kk < 16; ++kk) {
      double2 a01 = *(const double2*)&As[kk][4 * tm];
      double2 a23 = *(const double2*)&As[kk][4 * tm + 2];
      double2 b01 = *(const double2*)&Bs[kk][4 * tn];
      double2 b23 = *(const double2*)&Bs[kk][4 * tn + 2];
      double av[4] = {a01.x, a01.y, a23.x, a23.y};
      double bv[4] = {b01.x, b01.y, b23.x, b23.y};
#pragma unroll
      for (int r = 0; r < 4; ++r)
#pragma unroll
        for (int c = 0; c < 4; ++c) acc[r][c] = fma(av[r], bv[c], acc[r][c]);
    }
    __syncthreads();
  }
  double bn[4];
#pragma unroll
  for (int c = 0; c < 4; ++c) {
    int n = n0 + 4 * tn + c;
    double bv = 0.0;
    if (n < N) {
      if (bias1) bv += (double)bias1[n];
      if (bias2) bv += (double)bias2[n];
    }
    bn[c] = bv;
  }
  if (mode == 0) {
#pragma unroll
    for (int r = 0; r < 4; ++r) {
      int m = m0 + 4 * tm + r;
      float* cp = C + (size_t)m * ldc + n0 + 4 * tn;
      if (n0 + 4 * tn + 4 <= N) {
        float4 s = make_float4((float)(acc[r][0] + bn[0]), (float)(acc[r][1] + bn[1]),
                               (float)(acc[r][2] + bn[2]), (float)(acc[r][3] + bn[3]));
        *(float4*)cp = s;
      } else {
#pragma unroll
        for (int c = 0; c < 4; ++c)
          if (n0 + 4 * tn + c < N) cp[c] = (float)(acc[r][c] + bn[c]);
      }
    }
  } else {
    // XWt store: row = l*32 + b (m = b*128 + l), coalesced float4 in n
#pragma unroll
    for (int r = 0; r < 4; ++r) {
      int m = m0 + 4 * tm + r;
      int bb = m >> 7, l = m & 127;
      float* cp = C + ((size_t)l * 32 + bb) * G4 + n0 + 4 * tn;
      float4 s = make_float4((float)(acc[r][0] + bn[0]), (float)(acc[r][1] + bn[1]),
                             (float)(acc[r][2] + bn[2]), (float)(acc[r][3] + bn[3]));
      *(float4*)cp = s;
    }
  }
}

// ---------------- tiled GEMM f64-acc, C(+o*516 col) = A * B (B row-major), batched over o ----------------
__global__ __launch_bounds__(256) void k_gemm_nn(const float* __restrict__ A, int lda,
                                                 const float* __restrict__ Bm, int ldb,
                                                 size_t strideB,
                                                 float* __restrict__ C, int ldc,
                                                 int M, int N, int K) {
  __shared__ __align__(16) double As[16][68];
  __shared__ __align__(16) double Bs[16][68];
  int t = threadIdx.x;
  int o = blockIdx.z;
  const float* B = Bm + (size_t)o * strideB;
  float* Cb = C + (size_t)o * 516;
  int m0 = blockIdx.x * 64, n0 = blockIdx.y * 64;
  int tm = t & 15, tn = t >> 4;
  int ar = t >> 2, akq = t & 3;
  double acc[4][4];
#pragma unroll
  for (int r = 0; r < 4; ++r)
#pragma unroll
    for (int c = 0; c < 4; ++c) acc[r][c] = 0.0;

  for (int k0 = 0; k0 < K; k0 += 16) {
    {
      const float* ap = A + (size_t)(m0 + ar) * lda + k0 + 4 * akq;
      float v0, v1, v2, v3;
      if (k0 + 4 * akq + 4 <= K) {
        float4 f = *(const float4*)ap; v0 = f.x; v1 = f.y; v2 = f.z; v3 = f.w;
      } else {
        v0 = (k0 + 4 * akq + 0 < K) ? ap[0] : 0.f;
        v1 = (k0 + 4 * akq + 1 < K) ? ap[1] : 0.f;
        v2 = (k0 + 4 * akq + 2 < K) ? ap[2] : 0.f;
        v3 = (k0 + 4 * akq + 3 < K) ? ap[3] : 0.f;
      }
      As[4 * akq + 0][ar] = (double)v0; As[4 * akq + 1][ar] = (double)v1;
      As[4 * akq + 2][ar] = (double)v2; As[4 * akq + 3][ar] = (double)v3;
    }
    {
      int kr = k0 + (t >> 4);
      int nc = n0 + 4 * (t & 15);
      float v0 = 0.f, v1 = 0.f, v2 = 0.f, v3 = 0.f;
      if (kr < K) {
        const float* bp = B + (size_t)kr * ldb + nc;
        if (nc + 4 <= N) {
          float4 f = *(const float4*)bp; v0 = f.x; v1 = f.y; v2 = f.z; v3 = f.w;
        } else {
          if (nc + 0 < N) v0 = bp[0];
          if (nc + 1 < N) v1 = bp[1];
          if (nc + 2 < N) v2 = bp[2];
          if (nc + 3 < N) v3 = bp[3];
        }
      }
      int kk = t >> 4, nq = 4 * (t & 15);
      Bs[kk][nq + 0] = (double)v0; Bs[kk][nq + 1] = (double)v1;
      Bs[kk][nq + 2] = (double)v2; Bs[kk][nq + 3] = (double)v3;
    }
    __syncthreads();
#pragma unroll
    for (int kk = 0; kk < 16; ++kk) {
      double2 a01 = *(const double2*)&As[kk][4 * tm];
      double2 a23 = *(const double2*)&As[kk][4 * tm + 2];
      double2 b01 = *(const double2*)&Bs[kk][4 * tn];
      double2 b23 = *(const double2*)&Bs[kk][4 * tn + 2];
      double av[4] = {a01.x, a01.y, a23.x, a23.y};
      double bv[4] = {b01.x, b01.y, b23.x, b23.y};
#pragma unroll
      for (int r = 0; r < 4; ++r)
#pragma unroll
        for (int c = 0; c < 4; ++c) acc[r][c] = fma(av[r], bv[c], acc[r][c]);
    }
    __syncthreads();
  }
#pragma unroll
  for (int r = 0; r < 4; ++r) {
    int m = m0 + 4 * tm + r;
    float* cp = Cb + (size_t)m * ldc + n0 + 4 * tn;
    if (n0 + 4 * tn + 4 <= N) {
      *(float4*)cp = make_float4((float)acc[r][0], (float)acc[r][1],
                                 (float)acc[r][2], (float)acc[r][3]);
    } else {
#pragma unroll
      for (int c = 0; c < 4; ++c)
        if (n0 + 4 * tn + c < N) cp[c] = (float)acc[r][c];
    }
  }
}

// ---------------- persistent BiLSTM v4: whole-tile LDS residency, single poll/stage per step
// Block = (dir, 4-unit slice). gfx950 has 160 KB LDS/CU: the FULL h tile (400x32 f64 =
// 102.4 KB) plus Whh pre-converted to f64 (4x400x4 = 51.2 KB) both stay in LDS.
// Per step: ONE flag poll (wave w polls flags [25w,25w+25)), ONE coalesced stage of the
// whole tile, then an uninterrupted 100-iteration inner product with the K dimension
// split across lane quads (k ≡ lane&3 mod 4) and reduced via __shfl_xor — no LDS
// scratch round-trip, no bank-conflicted gpart phase. 3 barriers/step (was 8).
// Gates use f32 transcendentals (expf/tanhf): ~1e-7/step perturbation, sub-dominant to
// the f32 reference's own accumulation error; all GEMV accumulation / c / h stay f64.
// Publish protocol identical to v3: flag = #publishes, restage of step s requires all
// 100 flags >= s+1, which makes the parity-buffer overwrite WAR-safe.
__global__ __launch_bounds__(256, 1) void k_lstm3(const float* __restrict__ xwt,   // [2][128][32][1600] f32
                                                  const float* __restrict__ whh_f, // [1600][400]
                                                  const float* __restrict__ whh_b,
                                                  const int* __restrict__ word_idxs,
                                                  double* __restrict__ hbuf,       // [2][2][400][32] f64
                                                  unsigned* __restrict__ flags,    // [2][128] u32
                                                  float* __restrict__ enc) {
  __shared__ __align__(16) double Wvd[4 * 400 * 4];   // [u][k][g] f64, 51,200 B
  __shared__ __align__(16) double Shd[12800];          // h tile [k 0..399][b 0..31], 102,400 B
  int bid = blockIdx.x;
  int d = bid / 100, slice = bid - d * 100;
  const float* whh = d ? whh_b : whh_f;
  const float* xwd = xwt + (size_t)d * SEQL * 32 * G4;
  unsigned* flg = flags + (size_t)d * 128;
  int t = threadIdx.x;

  // one-time: stage Whh rows for our 4 units x 4 gates into LDS as f64 [u][k][g]
  for (int pp = 0; pp < 16; ++pp) {
    int u = pp >> 2, g = pp & 3;
    const float* src = whh + (size_t)(g * 400 + slice * 4 + u) * 400;
    for (int k = t; k < 400; k += 256) Wvd[((size_t)u * 400 + k) * 4 + g] = (double)src[k];
  }

  int su = t >> 6;          // wave id = unit index within slice (0..3)
  int p  = (t >> 2) & 15;   // batch-pair index (0..15)
  int sb2 = 2 * p;
  int kp = t & 3;           // k-phase within lane quad
  int kglob = slice * 4 + su;
  int lane = t & 63;
  int cb = sb2 + kp;        // this thread's batch column (valid for kp<2)
  double cst = 0.0;

  if (kp < 2)
    astore(&hbuf[((size_t)1 * 2 + d) * 12800 + (size_t)kglob * 32 + cb], 0.0);
  __syncthreads();                        // drain vmcnt (h init visible)
  if (t == 0) afstore(&flg[slice], 1u);   // publish #1 (initial h)

  for (int s = 0; s < SEQL; ++s) {
    int l = d ? (SEQL - 1 - s) : s;
    int rp = (s + 1) & 1, wp = s & 1;
    const double* hr = hbuf + ((size_t)rp * 2 + d) * 12800;
    double* hwb = hbuf + ((size_t)wp * 2 + d) * 12800;
    unsigned need = (unsigned)(s + 1);

    // prefetch xw gates + mask for (unit su, batch cb) — consumed at step end (latency hidden)
    float xw0 = 0.f, xw1 = 0.f, xw2 = 0.f, xw3 = 0.f;
    bool m = false;
    if (kp < 2) {
      const float* xp = xwd + ((size_t)l * 32 + cb) * G4 + kglob;
      xw0 = xp[0]; xw1 = xp[400]; xw2 = xp[800]; xw3 = xp[1200];
      m = word_idxs[cb * SEQL + l] > 0;
    }

    // single poll per step: wave su polls producer flags [su*25, su*25+25)
    {
      bool mine = lane < 25;
      const unsigned* fp = flg + su * 25 + lane;
      while (true) {
        unsigned v = mine ? afload(fp) : 0xFFFFFFFFu;
        if (__ballot(v < need) == 0ull) break;
        __builtin_amdgcn_s_sleep(1);
      }
    }
    __syncthreads();   // all 100 flags >= s+1; prior-step Shd consumption done

    // stage the full h tile (400x32 f64) — coalesced, conflict-free
#pragma unroll 5
    for (int i = t; i < 12800; i += 256) Shd[i] = aload(&hr[i]);
    __syncthreads();

    double acc[8];
#pragma unroll
    for (int z = 0; z < 8; ++z) acc[z] = 0.0;
#pragma unroll 4
    for (int kk = 0; kk < 100; ++kk) {
      int klocal = 4 * kk + kp;
      double2 hp = *(const double2*)&Shd[(size_t)klocal * 32 + sb2];
      const double2* wrow = (const double2*)&Wvd[((size_t)su * 400 + klocal) * 4];
      double2 w01 = wrow[0];   // gates i,f
      double2 w23 = wrow[1];   // gates g,o
      acc[0] = fma(w01.x, hp.x, acc[0]);
      acc[1] = fma(w01.x, hp.y, acc[1]);
      acc[2] = fma(w01.y, hp.x, acc[2]);
      acc[3] = fma(w01.y, hp.y, acc[3]);
      acc[4] = fma(w23.x, hp.x, acc[4]);
      acc[5] = fma(w23.x, hp.y, acc[5]);
      acc[6] = fma(w23.y, hp.x, acc[6]);
      acc[7] = fma(w23.y, hp.y, acc[7]);
    }
    // reduce the 4-way k-split within each lane quad (acc[g*2+j], j = batch offset)
#pragma unroll
    for (int z = 0; z < 8; ++z) {
      acc[z] += __shfl_xor(acc[z], 1);
      acc[z] += __shfl_xor(acc[z], 2);
    }

    if (kp < 2) {
      double gi = acc[0 + kp] + (double)xw0;
      double gf = acc[2 + kp] + (double)xw1;
      double gg = acc[4 + kp] + (double)xw2;
      double go = acc[6 + kp] + (double)xw3;
      double si = (double)(1.f / (1.f + expf(-(float)gi)));
      double sf = (double)(1.f / (1.f + expf(-(float)gf)));
      double so = (double)(1.f / (1.f + expf(-(float)go)));
      double cn = sf * cst + si * (double)tanhf((float)gg);
      double hn = so * (double)tanhf((float)cn);
      double holdv = Shd[(size_t)kglob * 32 + cb];   // own h from step s-1 (still resident)
      double hv = m ? hn : holdv;
      cst = m ? cn : cst;
      astore(&hwb[(size_t)kglob * 32 + cb], hv);
      enc[((size_t)cb * SEQL + l) * 800 + d * 400 + kglob] = m ? (float)hn : 0.f;
    }
    __syncthreads();                          // drain vmcnt: h stores visible
    if (t == 0) afstore(&flg[slice], (unsigned)(s + 2));   // publish
  }
}

// ---------------- stage 2: score + argmax per (b,x), emits sort keys ----------------
__global__ __launch_bounds__(128) void k_stage2(const float* __restrict__ U,
                                                const float* __restrict__ y1T,
                                                const int* __restrict__ labels,
                                                unsigned long long* __restrict__ keys) {
  __shared__ double Ur[4644];
  int bx = blockIdx.x;
  int b = bx >> 7, x = bx & 127;
  const float* Urow = U + (size_t)bx * 4644;
  for (int i = threadIdx.x; i < 4644; i += 128) Ur[i] = (double)Urow[i];
  __syncthreads();
  int y = threadIdx.x;
  double acc[9];
#pragma unroll
  for (int o = 0; o < 9; ++o) acc[o] = 0.0;
  const float* yb = y1T + (size_t)b * 513 * 128 + y;
  for (int j = 0; j < 513; ++j) {
    double yv = (double)yb[(size_t)j * 128];
#pragma unroll
    for (int o = 0; o < 9; ++o) acc[o] = fma(Ur[o * 516 + j], yv, acc[o]);
  }
  double best = acc[0];
  int bi = 0;
#pragma unroll
  for (int o = 1; o < 9; ++o) {
    if (acc[o] > best) { best = acc[o]; bi = o; }
  }
  int fi = x * 128 + y;
  int lab = labels[(size_t)bx * 128 + y];
  bool valid = (bi != 1) && (lab > 0);
  unsigned long long key;
  if (valid) {
    unsigned long long u = (unsigned long long)__double_as_longlong(best);
    unsigned long long mm = (u >> 63) ? ~u : (u | 0x8000000000000000ull);
    unsigned long long dm = ~mm;
    key = (dm & ~0x3FFFFull) | ((unsigned long long)(unsigned)fi << 4) |
          (unsigned long long)(unsigned)bi;
  } else {
    key = ~0ull;
  }
  keys[(size_t)b * 16384 + fi] = key;
}

// ---------------- decode helpers ----------------
__device__ __forceinline__ void rangemask(int i, int j,
                                          unsigned long long& r0, unsigned long long& r1) {
  if (i > j) { r0 = 0ull; r1 = 0ull; return; }
  unsigned long long u0, u1;
  if (j >= 64) { u0 = ~0ull; u1 = (j >= 127) ? ~0ull : ((1ull << (j - 63)) - 1ull); }
  else         { u0 = (j == 63) ? ~0ull : ((1ull << (j + 1)) - 1ull); u1 = 0ull; }
  unsigned long long f0, f1;
  if (i >= 64) { f0 = 0ull; f1 = (~0ull) << (i - 64); }
  else         { f0 = (~0ull) << i; f1 = ~0ull; }
  r0 = u0 & f0; r1 = u1 & f1;
}

// ---------------- decode: sort + greedy NMS scan, one block per sentence ----------------
__global__ __launch_bounds__(1024) void k_decode(unsigned long long* __restrict__ keysg,
                                                 int* __restrict__ outp) {
  extern __shared__ unsigned long long lds[];
  int b = blockIdx.x;
  int t = threadIdx.x;
  unsigned long long* kg = keysg + (size_t)b * 16384;
  int* ob = outp + (size_t)b * 16384;

  for (int i = t; i < 16384; i += 1024) ob[i] = 1;
  __syncthreads();

  for (int hhalf = 0; hhalf < 2; ++hhalf) {
    for (int i = t; i < 8192; i += 1024) lds[i] = kg[hhalf * 8192 + i];
    __syncthreads();
    bool desc = (hhalf == 1);
    for (int k = 2; k <= 8192; k <<= 1) {
      for (int j = k >> 1; j > 0; j >>= 1) {
        for (int p = 0; p < 8; ++p) {
          int i = p * 1024 + t;
          int ix = i ^ j;
          if (ix > i) {
            unsigned long long ka = lds[i], kb = lds[ix];
            bool up = (((i & k) == 0) != desc);
            if (up ? (ka > kb) : (ka < kb)) { lds[i] = kb; lds[ix] = ka; }
          }
        }
        __syncthreads();
      }
    }
    for (int i = t; i < 8192; i += 1024) kg[hhalf * 8192 + i] = lds[i];
    __syncthreads();
  }
  for (int i = t; i < 8192; i += 1024) {
    unsigned long long ka = kg[i], kb = kg[i + 8192];
    if (ka > kb) { kg[i] = kb; kg[i + 8192] = ka; }
  }
  __syncthreads();
  for (int hhalf = 0; hhalf < 2; ++hhalf) {
    for (int i = t; i < 8192; i += 1024) lds[i] = kg[hhalf * 8192 + i];
    __syncthreads();
    for (int j = 4096; j > 0; j >>= 1) {
      for (int p = 0; p < 8; ++p) {
        int i = p * 1024 + t;
        int ix = i ^ j;
        if (ix > i) {
          unsigned long long ka = lds[i], kb = lds[ix];
          if (ka > kb) { lds[i] = kb; lds[ix] = ka; }
        }
      }
      __syncthreads();
    }
    for (int i = t; i < 8192; i += 1024) kg[hhalf * 8192 + i] = lds[i];
    __syncthreads();
  }

  if (t < 64) {
    const int lane = t;
    unsigned long long s0 = 0, s1 = 0, in0 = 0, in1 = 0;
    for (int base = 0; base < 16384; base += 64) {
      unsigned long long key = kg[base + lane];
      bool valid = (key != ~0ull);
      if (__ballot(valid) == 0ull) break;
      int fi = (int)((key >> 4) & 0x3FFFull);
      int ci = fi >> 7, cj = fi & 127, ca = (int)(key & 15ull);
      bool alive = valid;
      while (true) {
        bool conflict = false;
        {
          unsigned long long r0, r1;
          rangemask(ci, cj, r0, r1);
          if (((r0 & s0) | (r1 & s1)) != 0ull) conflict = true;
          unsigned long long ib = (ci < 64) ? (in0 >> ci) : (in1 >> (ci - 64));
          if (ib & 1ull) conflict = true;
        }
        unsigned long long elig = __ballot(alive && !conflict);
        if (elig == 0ull) break;
        int w = __ffsll((long long)elig) - 1;
        int wi = __shfl(ci, w), wj = __shfl(cj, w);
        if (lane == w) ob[fi] = ca;
        unsigned long long r0, r1;
        rangemask(wi, wj, r0, r1);
        in0 |= r0; in1 |= r1;
        if (wi < 64) s0 |= (1ull << wi); else s1 |= (1ull << (wi - 64));
        alive = alive && (lane > w);
      }
    }
  }
}

extern "C" void kernel_launch(void* const* d_in, const int* in_sizes, int n_in,
                              void* d_out, int out_size, void* d_ws, size_t ws_size,
                              hipStream_t stream) {
  const int*   word_idxs = (const int*)d_in[0];
  const int*   labels    = (const int*)d_in[1];
  const float* word_emb  = (const float*)d_in[2];
  const float* Wih_f = (const float*)d_in[3];
  const float* Whh_f = (const float*)d_in[4];
  const float* bih_f = (const float*)d_in[5];
  const float* bhh_f = (const float*)d_in[6];
  const float* Wih_b = (const float*)d_in[7];
  const float* Whh_b = (const float*)d_in[8];
  const float* bih_b = (const float*)d_in[9];
  const float* bhh_b = (const float*)d_in[10];
  const float* W_start = (const float*)d_in[11];
  const float* b_start = (const float*)d_in[12];
  const float* W_end   = (const float*)d_in[13];
  const float* b_end   = (const float*)d_in[14];
  const float* W_bi    = (const float*)d_in[15];

  char* ws = (char*)d_ws;
  float* x    = (float*)(ws + OFF_X);
  double* hbuf = (double*)(ws + OFF_HBUF);
  unsigned* flags = (unsigned*)(ws + OFF_FLG);
  float* XWt  = (float*)(ws + OFF_XW);
  float* he   = (float*)(ws + OFF_HE);
  float* enc  = (float*)(ws + OFF_ENC);
  float* U    = (float*)(ws + OFF_U);
  float* x1   = (float*)(ws + OFF_X1);
  float* y1T  = (float*)(ws + OFF_Y1T);
  float* Wbp  = (float*)(ws + OFF_WBP);
  unsigned long long* keys = (unsigned long long*)(ws + OFF_KEYS);
  int* outp = (int*)d_out;

  // 1. embedding gather
  k_gather<<<4096, 256, 0, stream>>>(word_idxs, word_emb, x);
  // 2. input-gate GEMMs, bias folded, stored coalesced as XWt[d][l][b][1600]
  dim3 g2(64, 25);
  k_gemm_nt<<<g2, 256, 0, stream>>>(x, EMBD, Wih_f, EMBD, bih_f, bhh_f,
                                    XWt, 0, 4096, G4, EMBD, 2);
  k_gemm_nt<<<g2, 256, 0, stream>>>(x, EMBD, Wih_b, EMBD, bih_b, bhh_b,
                                    XWt + (size_t)SEQL * 32 * G4, 0, 4096, G4, EMBD, 2);
  // 3. flags zero (x region now dead), then persistent LSTM (flag-synced)
  hipMemsetAsync(ws + OFF_FLG, 0, 4096, stream);
  k_lstm3<<<NBLK, 256, 0, stream>>>(XWt, Whh_f, Whh_b, word_idxs, hbuf, flags, enc);
  // 4. projections: x1 (coalesced) and he (coalesced) -> y1T via LDS transpose
  dim3 g4(64, 8);
  k_gemm_nt<<<g4, 256, 0, stream>>>(enc, 800, W_start, 800, b_start, nullptr,
                                    x1, 516, 4096, FF, 800, 0);
  k_gemm_nt<<<g4, 256, 0, stream>>>(enc, 800, W_end, 800, b_end, nullptr,
                                    he, 512, 4096, FF, 800, 0);
  dim3 gt(16, 4, 32);
  k_y1t<<<gt, 256, 0, stream>>>(he, y1T);
  k_ones<<<32, 256, 0, stream>>>(x1, y1T);
  // 5. biaffine stage 1: U[b,x][o][j] = sum_i x1[b,x,i] W[o,i,j]
  k_wbpad<<<(9 * 513 * 516 + 255) / 256, 256, 0, stream>>>(W_bi, Wbp);
  dim3 g5(64, 9, 9);
  k_gemm_nn<<<g5, 256, 0, stream>>>(x1, 516, Wbp, 516, (size_t)513 * 516,
                                    U, 4644, 4096, 513, 513);
  // 6. stage 2 + argmax + key build
  k_stage2<<<4096, 128, 0, stream>>>(U, y1T, labels, keys);
  // 7. sort + greedy NMS decode
  k_decode<<<32, 1024, 65536, stream>>>(keys, outp);
}

// Round 2
// 4022.266 us; speedup vs baseline: 1.5402x; 1.5402x over previous
//
#include <hip/hip_runtime.h>
#include <math.h>

// Problem constants
#define SEQL 128
#define NB   32
#define EMBD 300
#define HH   400      // hidden per direction
#define G4   1600     // 4*HH
#define FF   512
#define NLAB 9
#define NBLK 200      // persistent LSTM blocks: 2 dirs x 100 slices (4 hidden units each)

// ---------------- workspace layout (bytes) ----------------
static const size_t OFF_X    = 0;          // x [4096][300] f32 — dead after input GEMMs
static const size_t OFF_HBUF = 0;          // h double-buffer [2][2][400][32] f64 (819,200) — live only in k_lstm3
static const size_t OFF_FLG  = 1048576;    // publish flags [2][128] u32 — in dead x region
static const size_t OFF_XW   = 5242880;    // XWt [2][128][32][1600] f32 (52,428,800) dead after LSTM; he reuses it
static const size_t OFF_HE   = 5242880;    // he [4096][512] f32 (8,388,608) — after LSTM, before gemm_nn
static const size_t OFF_ENC  = 62914560;   // enc [4096][800] f32 (13,107,200) dead after proj GEMMs
static const size_t OFF_U    = 0;          // U [4096][9][516] f32 (76,087,296) overlays all of the above post-proj
static const size_t OFF_X1   = 76087296;   // x1 [4096][516] (8,454,144)
static const size_t OFF_Y1T  = 84541440;   // y1T [32][513][128] (8,404,992)
static const size_t OFF_KEYS = 92946432;   // keys u64 [32][16384] (4,194,304)
static const size_t OFF_WBP  = 97140736;   // Wb padded [9][513][516] (9,529,488)

// ---------------- agent-scope (IF-coherent, cache-bypassing) accessors ----------------
__device__ __forceinline__ double aload(const double* p) {
  return __hip_atomic_load(p, __ATOMIC_RELAXED, __HIP_MEMORY_SCOPE_AGENT);
}
__device__ __forceinline__ void astore(double* p, double v) {
  __hip_atomic_store(p, v, __ATOMIC_RELAXED, __HIP_MEMORY_SCOPE_AGENT);
}
__device__ __forceinline__ unsigned afload(const unsigned* p) {
  return __hip_atomic_load(p, __ATOMIC_RELAXED, __HIP_MEMORY_SCOPE_AGENT);
}
__device__ __forceinline__ void afstore(unsigned* p, unsigned v) {
  __hip_atomic_store(p, v, __ATOMIC_RELAXED, __HIP_MEMORY_SCOPE_AGENT);
}

// ---------------- embedding gather ----------------
__global__ __launch_bounds__(256) void k_gather(const int* __restrict__ wi,
                                                const float* __restrict__ emb,
                                                float* __restrict__ x) {
  int m = blockIdx.x;
  int idx = wi[m];
  const float* src = emb + (size_t)idx * EMBD;
  float* dst = x + (size_t)m * EMBD;
  for (int e = threadIdx.x; e < EMBD; e += 256) dst[e] = src[e];
}

// ---------------- W_biaffine pad to stride 516 ----------------
__global__ __launch_bounds__(256) void k_wbpad(const float* __restrict__ wbi,
                                               float* __restrict__ wbp) {
  int tid = blockIdx.x * 256 + threadIdx.x;
  const int PER = 513 * 516;
  if (tid >= 9 * PER) return;
  int o = tid / PER;
  int r = tid - o * PER;
  int i = r / 516;
  int j = r - i * 516;
  wbp[tid] = (j < 513) ? wbi[(size_t)o * 513 * 513 + (size_t)i * 513 + j] : 0.f;
}

// ---------------- ones columns ----------------
__global__ __launch_bounds__(256) void k_ones(float* __restrict__ x1, float* __restrict__ y1T) {
  int tid = blockIdx.x * 256 + threadIdx.x;
  if (tid < 4096) {
    x1[(size_t)tid * 516 + 512] = 1.f;
  } else if (tid < 8192) {
    int r = tid - 4096;
    int bb = r >> 7, y = r & 127;
    y1T[((size_t)bb * 513 + 512) * 128 + y] = 1.f;
  }
}

// ---------------- he -> y1T transpose (coalesced both sides) ----------------
__global__ __launch_bounds__(256) void k_y1t(const float* __restrict__ he,
                                             float* __restrict__ y1T) {
  __shared__ float tile[32][33];
  int b = blockIdx.z;
  int n0 = blockIdx.x * 32, y0 = blockIdx.y * 32;
  int tx = threadIdx.x & 31, ty = threadIdx.x >> 5;
  for (int yy = ty; yy < 32; yy += 8)
    tile[yy][tx] = he[((size_t)b * 128 + y0 + yy) * 512 + n0 + tx];
  __syncthreads();
  for (int nn = ty; nn < 32; nn += 8)
    y1T[((size_t)b * 513 + n0 + nn) * 128 + y0 + tx] = tile[tx][nn];
}

// ---------------- tiled GEMM, f64 accumulate, f32 LDS staging (exact: cvt after read)
// mode 0: normal store (ldc); mode 2: XWt store [l][b][n] (coalesced)
__global__ __launch_bounds__(256) void k_gemm_nt(const float* __restrict__ A, int lda,
                                                 const float* __restrict__ W, int ldw,
                                                 const float* __restrict__ bias1,
                                                 const float* __restrict__ bias2,
                                                 float* __restrict__ C, int ldc,
                                                 int M, int N, int K, int mode) {
  __shared__ __align__(16) float As[16][68];
  __shared__ __align__(16) float Bs[16][68];
  int t = threadIdx.x;
  int m0 = blockIdx.x * 64, n0 = blockIdx.y * 64;
  int tm = t & 15, tn = t >> 4;
  int ar = t >> 2, akq = t & 3;
  double acc[4][4];
#pragma unroll
  for (int r = 0; r < 4; ++r)
#pragma unroll
    for (int c = 0; c < 4; ++c) acc[r][c] = 0.0;

  for (int k0 = 0; k0 < K; k0 += 16) {
    {
      const float* ap = A + (size_t)(m0 + ar) * lda + k0 + 4 * akq;
      float v0, v1, v2, v3;
      if (k0 + 4 * akq + 4 <= K) {
        float4 f = *(const float4*)ap; v0 = f.x; v1 = f.y; v2 = f.z; v3 = f.w;
      } else {
        v0 = (k0 + 4 * akq + 0 < K) ? ap[0] : 0.f;
        v1 = (k0 + 4 * akq + 1 < K) ? ap[1] : 0.f;
        v2 = (k0 + 4 * akq + 2 < K) ? ap[2] : 0.f;
        v3 = (k0 + 4 * akq + 3 < K) ? ap[3] : 0.f;
      }
      As[4 * akq + 0][ar] = v0; As[4 * akq + 1][ar] = v1;
      As[4 * akq + 2][ar] = v2; As[4 * akq + 3][ar] = v3;
    }
    {
      int nr = n0 + ar;
      float v0 = 0.f, v1 = 0.f, v2 = 0.f, v3 = 0.f;
      if (nr < N) {
        const float* wp = W + (size_t)nr * ldw + k0 + 4 * akq;
        if (k0 + 4 * akq + 4 <= K) {
          float4 f = *(const float4*)wp; v0 = f.x; v1 = f.y; v2 = f.z; v3 = f.w;
        } else {
          if (k0 + 4 * akq + 0 < K) v0 = wp[0];
          if (k0 + 4 * akq + 1 < K) v1 = wp[1];
          if (k0 + 4 * akq + 2 < K) v2 = wp[2];
          if (k0 + 4 * akq + 3 < K) v3 = wp[3];
        }
      }
      Bs[4 * akq + 0][ar] = v0; Bs[4 * akq + 1][ar] = v1;
      Bs[4 * akq + 2][ar] = v2; Bs[4 * akq + 3][ar] = v3;
    }
    __syncthreads();
#pragma unroll
    for (int kk = 0; kk < 16; ++kk) {
      float4 a4 = *(const float4*)&As[kk][4 * tm];
      float4 b4 = *(const float4*)&Bs[kk][4 * tn];
      double av[4] = {(double)a4.x, (double)a4.y, (double)a4.z, (double)a4.w};
      double bv[4] = {(double)b4.x, (double)b4.y, (double)b4.z, (double)b4.w};
#pragma unroll
      for (int r = 0; r < 4; ++r)
#pragma unroll
        for (int c = 0; c < 4; ++c) acc[r][c] = fma(av[r], bv[c], acc[r][c]);
    }
    __syncthreads();
  }
  double bn[4];
#pragma unroll
  for (int c = 0; c < 4; ++c) {
    int n = n0 + 4 * tn + c;
    double bv = 0.0;
    if (n < N) {
      if (bias1) bv += (double)bias1[n];
      if (bias2) bv += (double)bias2[n];
    }
    bn[c] = bv;
  }
  if (mode == 0) {
#pragma unroll
    for (int r = 0; r < 4; ++r) {
      int m = m0 + 4 * tm + r;
      float* cp = C + (size_t)m * ldc + n0 + 4 * tn;
      if (n0 + 4 * tn + 4 <= N) {
        float4 s = make_float4((float)(acc[r][0] + bn[0]), (float)(acc[r][1] + bn[1]),
                               (float)(acc[r][2] + bn[2]), (float)(acc[r][3] + bn[3]));
        *(float4*)cp = s;
      } else {
#pragma unroll
        for (int c = 0; c < 4; ++c)
          if (n0 + 4 * tn + c < N) cp[c] = (float)(acc[r][c] + bn[c]);
      }
    }
  } else {
    // XWt store: row = l*32 + b (m = b*128 + l), coalesced float4 in n
#pragma unroll
    for (int r = 0; r < 4; ++r) {
      int m = m0 + 4 * tm + r;
      int bb = m >> 7, l = m & 127;
      float* cp = C + ((size_t)l * 32 + bb) * G4 + n0 + 4 * tn;
      float4 s = make_float4((float)(acc[r][0] + bn[0]), (float)(acc[r][1] + bn[1]),
                             (float)(acc[r][2] + bn[2]), (float)(acc[r][3] + bn[3]));
      *(float4*)cp = s;
    }
  }
}

// ---------------- tiled GEMM f64-acc, f32 LDS staging, batched over o ----------------
__global__ __launch_bounds__(256) void k_gemm_nn(const float* __restrict__ A, int lda,
                                                 const float* __restrict__ Bm, int ldb,
                                                 size_t strideB,
                                                 float* __restrict__ C, int ldc,
                                                 int M, int N, int K) {
  __shared__ __align__(16) float As[16][68];
  __shared__ __align__(16) float Bs[16][68];
  int t = threadIdx.x;
  int o = blockIdx.z;
  const float* B = Bm + (size_t)o * strideB;
  float* Cb = C + (size_t)o * 516;
  int m0 = blockIdx.x * 64, n0 = blockIdx.y * 64;
  int tm = t & 15, tn = t >> 4;
  int ar = t >> 2, akq = t & 3;
  double acc[4][4];
#pragma unroll
  for (int r = 0; r < 4; ++r)
#pragma unroll
    for (int c = 0; c < 4; ++c) acc[r][c] = 0.0;

  for (int k0 = 0; k0 < K; k0 += 16) {
    {
      const float* ap = A + (size_t)(m0 + ar) * lda + k0 + 4 * akq;
      float v0, v1, v2, v3;
      if (k0 + 4 * akq + 4 <= K) {
        float4 f = *(const float4*)ap; v0 = f.x; v1 = f.y; v2 = f.z; v3 = f.w;
      } else {
        v0 = (k0 + 4 * akq + 0 < K) ? ap[0] : 0.f;
        v1 = (k0 + 4 * akq + 1 < K) ? ap[1] : 0.f;
        v2 = (k0 + 4 * akq + 2 < K) ? ap[2] : 0.f;
        v3 = (k0 + 4 * akq + 3 < K) ? ap[3] : 0.f;
      }
      As[4 * akq + 0][ar] = v0; As[4 * akq + 1][ar] = v1;
      As[4 * akq + 2][ar] = v2; As[4 * akq + 3][ar] = v3;
    }
    {
      int kr = k0 + (t >> 4);
      int nc = n0 + 4 * (t & 15);
      float v0 = 0.f, v1 = 0.f, v2 = 0.f, v3 = 0.f;
      if (kr < K) {
        const float* bp = B + (size_t)kr * ldb + nc;
        if (nc + 4 <= N) {
          float4 f = *(const float4*)bp; v0 = f.x; v1 = f.y; v2 = f.z; v3 = f.w;
        } else {
          if (nc + 0 < N) v0 = bp[0];
          if (nc + 1 < N) v1 = bp[1];
          if (nc + 2 < N) v2 = bp[2];
          if (nc + 3 < N) v3 = bp[3];
        }
      }
      int kk = t >> 4, nq = 4 * (t & 15);
      Bs[kk][nq + 0] = v0; Bs[kk][nq + 1] = v1;
      Bs[kk][nq + 2] = v2; Bs[kk][nq + 3] = v3;
    }
    __syncthreads();
#pragma unroll
    for (int kk = 0; kk < 16; ++kk) {
      float4 a4 = *(const float4*)&As[kk][4 * tm];
      float4 b4 = *(const float4*)&Bs[kk][4 * tn];
      double av[4] = {(double)a4.x, (double)a4.y, (double)a4.z, (double)a4.w};
      double bv[4] = {(double)b4.x, (double)b4.y, (double)b4.z, (double)b4.w};
#pragma unroll
      for (int r = 0; r < 4; ++r)
#pragma unroll
        for (int c = 0; c < 4; ++c) acc[r][c] = fma(av[r], bv[c], acc[r][c]);
    }
    __syncthreads();
  }
#pragma unroll
  for (int r = 0; r < 4; ++r) {
    int m = m0 + 4 * tm + r;
    float* cp = Cb + (size_t)m * ldc + n0 + 4 * tn;
    if (n0 + 4 * tn + 4 <= N) {
      *(float4*)cp = make_float4((float)acc[r][0], (float)acc[r][1],
                                 (float)acc[r][2], (float)acc[r][3]);
    } else {
#pragma unroll
      for (int c = 0; c < 4; ++c)
        if (n0 + 4 * tn + c < N) cp[c] = (float)acc[r][c];
    }
  }
}

// ---------------- persistent BiLSTM v5: MLP-staged h tile + conflict-free inner reads
// v4 post-mortem: (a) stage was latency-exposed (load->ds_write pairs, ~5 deep); now all
// 50 agent loads per thread issue into registers first (static-index unrolled array), then
// 50 ds_writes — 50 outstanding loads, stage ~= L3 latency + BW instead of 50/5 round trips.
// (b) inner Shd double2 read had kp-independent bank quads (8-way conflict, 1.23e8 cycles);
// lane remap kp=lane>>4, p=lane&15 makes each 8-lane group cover 128 consecutive bytes =
// all 32 banks once — conflict-free. shfl_xor masks 1/2 -> 16/32 (same summation tree,
// bit-identical). All math identical to v4.
__global__ __launch_bounds__(256, 1) void k_lstm3(const float* __restrict__ xwt,   // [2][128][32][1600] f32
                                                  const float* __restrict__ whh_f, // [1600][400]
                                                  const float* __restrict__ whh_b,
                                                  const int* __restrict__ word_idxs,
                                                  double* __restrict__ hbuf,       // [2][2][400][32] f64
                                                  unsigned* __restrict__ flags,    // [2][128] u32
                                                  float* __restrict__ enc) {
  __shared__ __align__(16) double Wvd[4 * 400 * 4];   // [u][k][g] f64, 51,200 B
  __shared__ __align__(16) double Shd[12800];          // h tile [k 0..399][b 0..31], 102,400 B
  int bid = blockIdx.x;
  int d = bid / 100, slice = bid - d * 100;
  const float* whh = d ? whh_b : whh_f;
  const float* xwd = xwt + (size_t)d * SEQL * 32 * G4;
  unsigned* flg = flags + (size_t)d * 128;
  int t = threadIdx.x;

  // one-time: stage Whh rows for our 4 units x 4 gates into LDS as f64 [u][k][g]
  for (int pp = 0; pp < 16; ++pp) {
    int u = pp >> 2, g = pp & 3;
    const float* src = whh + (size_t)(g * 400 + slice * 4 + u) * 400;
    for (int k = t; k < 400; k += 256) Wvd[((size_t)u * 400 + k) * 4 + g] = (double)src[k];
  }

  int su = t >> 6;          // wave id = unit index within slice (0..3)
  int lane = t & 63;
  int kp = lane >> 4;       // k-phase (0..3) — high lane bits: conflict-free Shd reads
  int p  = lane & 15;       // batch-pair index (0..15)
  int sb2 = 2 * p;
  int kglob = slice * 4 + su;
  int cb = sb2 + kp;        // this thread's batch column (valid for kp<2)
  double cst = 0.0;

  if (kp < 2)
    astore(&hbuf[((size_t)1 * 2 + d) * 12800 + (size_t)kglob * 32 + cb], 0.0);
  __syncthreads();                        // drain vmcnt (h init visible)
  if (t == 0) afstore(&flg[slice], 1u);   // publish #1 (initial h)

  for (int s = 0; s < SEQL; ++s) {
    int l = d ? (SEQL - 1 - s) : s;
    int rp = (s + 1) & 1, wp = s & 1;
    const double* hr = hbuf + ((size_t)rp * 2 + d) * 12800;
    double* hwb = hbuf + ((size_t)wp * 2 + d) * 12800;
    unsigned need = (unsigned)(s + 1);

    // prefetch xw gates + mask for (unit su, batch cb) — consumed at step end (latency hidden)
    float xw0 = 0.f, xw1 = 0.f, xw2 = 0.f, xw3 = 0.f;
    bool m = false;
    if (kp < 2) {
      const float* xp = xwd + ((size_t)l * 32 + cb) * G4 + kglob;
      xw0 = xp[0]; xw1 = xp[400]; xw2 = xp[800]; xw3 = xp[1200];
      m = word_idxs[cb * SEQL + l] > 0;
    }

    // single poll per step: wave su polls producer flags [su*25, su*25+25)
    {
      bool mine = lane < 25;
      const unsigned* fp = flg + su * 25 + lane;
      while (true) {
        unsigned v = mine ? afload(fp) : 0xFFFFFFFFu;
        if (__ballot(v < need) == 0ull) break;
        __builtin_amdgcn_s_sleep(1);
      }
    }
    __syncthreads();   // all 100 flags >= s+1; prior-step Shd consumption done

    // stage the full h tile (400x32 f64): issue ALL 50 loads, then write LDS.
    // Static-index register array -> 50 outstanding agent loads (MLP), no per-pair waits.
    {
      double r[50];
#pragma unroll
      for (int j = 0; j < 50; ++j) r[j] = aload(&hr[t + 256 * j]);
#pragma unroll
      for (int j = 0; j < 50; ++j) Shd[t + 256 * j] = r[j];
    }
    __syncthreads();

    double acc[8];
#pragma unroll
    for (int z = 0; z < 8; ++z) acc[z] = 0.0;
#pragma unroll 4
    for (int kk = 0; kk < 100; ++kk) {
      int klocal = 4 * kk + kp;
      double2 hp = *(const double2*)&Shd[(size_t)klocal * 32 + sb2];
      const double2* wrow = (const double2*)&Wvd[((size_t)su * 400 + klocal) * 4];
      double2 w01 = wrow[0];   // gates i,f
      double2 w23 = wrow[1];   // gates g,o
      acc[0] = fma(w01.x, hp.x, acc[0]);
      acc[1] = fma(w01.x, hp.y, acc[1]);
      acc[2] = fma(w01.y, hp.x, acc[2]);
      acc[3] = fma(w01.y, hp.y, acc[3]);
      acc[4] = fma(w23.x, hp.x, acc[4]);
      acc[5] = fma(w23.x, hp.y, acc[5]);
      acc[6] = fma(w23.y, hp.x, acc[6]);
      acc[7] = fma(w23.y, hp.y, acc[7]);
    }
    // reduce the 4-way k-split across kp groups (lane bits 4,5) — same tree as v4
#pragma unroll
    for (int z = 0; z < 8; ++z) {
      acc[z] += __shfl_xor(acc[z], 16);
      acc[z] += __shfl_xor(acc[z], 32);
    }

    if (kp < 2) {
      double gi = acc[0 + kp] + (double)xw0;
      double gf = acc[2 + kp] + (double)xw1;
      double gg = acc[4 + kp] + (double)xw2;
      double go = acc[6 + kp] + (double)xw3;
      double si = (double)(1.f / (1.f + expf(-(float)gi)));
      double sf = (double)(1.f / (1.f + expf(-(float)gf)));
      double so = (double)(1.f / (1.f + expf(-(float)go)));
      double cn = sf * cst + si * (double)tanhf((float)gg);
      double hn = so * (double)tanhf((float)cn);
      double holdv = Shd[(size_t)kglob * 32 + cb];   // own h from step s-1 (still resident)
      double hv = m ? hn : holdv;
      cst = m ? cn : cst;
      astore(&hwb[(size_t)kglob * 32 + cb], hv);
      enc[((size_t)cb * SEQL + l) * 800 + d * 400 + kglob] = m ? (float)hn : 0.f;
    }
    __syncthreads();                          // drain vmcnt: h stores visible
    if (t == 0) afstore(&flg[slice], (unsigned)(s + 2));   // publish
  }
}

// ---------------- stage 2: score + argmax per (b,x), emits sort keys ----------------
__global__ __launch_bounds__(128) void k_stage2(const float* __restrict__ U,
                                                const float* __restrict__ y1T,
                                                const int* __restrict__ labels,
                                                unsigned long long* __restrict__ keys) {
  __shared__ double Ur[4644];
  int bx = blockIdx.x;
  int b = bx >> 7, x = bx & 127;
  const float* Urow = U + (size_t)bx * 4644;
  for (int i = threadIdx.x; i < 4644; i += 128) Ur[i] = (double)Urow[i];
  __syncthreads();
  int y = threadIdx.x;
  double acc[9];
#pragma unroll
  for (int o = 0; o < 9; ++o) acc[o] = 0.0;
  const float* yb = y1T + (size_t)b * 513 * 128 + y;
  for (int j = 0; j < 513; ++j) {
    double yv = (double)yb[(size_t)j * 128];
#pragma unroll
    for (int o = 0; o < 9; ++o) acc[o] = fma(Ur[o * 516 + j], yv, acc[o]);
  }
  double best = acc[0];
  int bi = 0;
#pragma unroll
  for (int o = 1; o < 9; ++o) {
    if (acc[o] > best) { best = acc[o]; bi = o; }
  }
  int fi = x * 128 + y;
  int lab = labels[(size_t)bx * 128 + y];
  bool valid = (bi != 1) && (lab > 0);
  unsigned long long key;
  if (valid) {
    unsigned long long u = (unsigned long long)__double_as_longlong(best);
    unsigned long long mm = (u >> 63) ? ~u : (u | 0x8000000000000000ull);
    unsigned long long dm = ~mm;
    key = (dm & ~0x3FFFFull) | ((unsigned long long)(unsigned)fi << 4) |
          (unsigned long long)(unsigned)bi;
  } else {
    key = ~0ull;
  }
  keys[(size_t)b * 16384 + fi] = key;
}

// ---------------- decode helpers ----------------
__device__ __forceinline__ void rangemask(int i, int j,
                                          unsigned long long& r0, unsigned long long& r1) {
  if (i > j) { r0 = 0ull; r1 = 0ull; return; }
  unsigned long long u0, u1;
  if (j >= 64) { u0 = ~0ull; u1 = (j >= 127) ? ~0ull : ((1ull << (j - 63)) - 1ull); }
  else         { u0 = (j == 63) ? ~0ull : ((1ull << (j + 1)) - 1ull); u1 = 0ull; }
  unsigned long long f0, f1;
  if (i >= 64) { f0 = 0ull; f1 = (~0ull) << (i - 64); }
  else         { f0 = (~0ull) << i; f1 = ~0ull; }
  r0 = u0 & f0; r1 = u1 & f1;
}

// ---------------- decode: sort + greedy NMS scan, one block per sentence ----------------
__global__ __launch_bounds__(1024) void k_decode(unsigned long long* __restrict__ keysg,
                                                 int* __restrict__ outp) {
  extern __shared__ unsigned long long lds[];
  int b = blockIdx.x;
  int t = threadIdx.x;
  unsigned long long* kg = keysg + (size_t)b * 16384;
  int* ob = outp + (size_t)b * 16384;

  for (int i = t; i < 16384; i += 1024) ob[i] = 1;
  __syncthreads();

  for (int hhalf = 0; hhalf < 2; ++hhalf) {
    for (int i = t; i < 8192; i += 1024) lds[i] = kg[hhalf * 8192 + i];
    __syncthreads();
    bool desc = (hhalf == 1);
    for (int k = 2; k <= 8192; k <<= 1) {
      for (int j = k >> 1; j > 0; j >>= 1) {
        for (int p = 0; p < 8; ++p) {
          int i = p * 1024 + t;
          int ix = i ^ j;
          if (ix > i) {
            unsigned long long ka = lds[i], kb = lds[ix];
            bool up = (((i & k) == 0) != desc);
            if (up ? (ka > kb) : (ka < kb)) { lds[i] = kb; lds[ix] = ka; }
          }
        }
        __syncthreads();
      }
    }
    for (int i = t; i < 8192; i += 1024) kg[hhalf * 8192 + i] = lds[i];
    __syncthreads();
  }
  for (int i = t; i < 8192; i += 1024) {
    unsigned long long ka = kg[i], kb = kg[i + 8192];
    if (ka > kb) { kg[i] = kb; kg[i + 8192] = ka; }
  }
  __syncthreads();
  for (int hhalf = 0; hhalf < 2; ++hhalf) {
    for (int i = t; i < 8192; i += 1024) lds[i] = kg[hhalf * 8192 + i];
    __syncthreads();
    for (int j = 4096; j > 0; j >>= 1) {
      for (int p = 0; p < 8; ++p) {
        int i = p * 1024 + t;
        int ix = i ^ j;
        if (ix > i) {
          unsigned long long ka = lds[i], kb = lds[ix];
          if (ka > kb) { lds[i] = kb; lds[ix] = ka; }
        }
      }
      __syncthreads();
    }
    for (int i = t; i < 8192; i += 1024) kg[hhalf * 8192 + i] = lds[i];
    __syncthreads();
  }

  if (t < 64) {
    const int lane = t;
    unsigned long long s0 = 0, s1 = 0, in0 = 0, in1 = 0;
    for (int base = 0; base < 16384; base += 64) {
      unsigned long long key = kg[base + lane];
      bool valid = (key != ~0ull);
      if (__ballot(valid) == 0ull) break;
      int fi = (int)((key >> 4) & 0x3FFFull);
      int ci = fi >> 7, cj = fi & 127, ca = (int)(key & 15ull);
      bool alive = valid;
      while (true) {
        bool conflict = false;
        {
          unsigned long long r0, r1;
          rangemask(ci, cj, r0, r1);
          if (((r0 & s0) | (r1 & s1)) != 0ull) conflict = true;
          unsigned long long ib = (ci < 64) ? (in0 >> ci) : (in1 >> (ci - 64));
          if (ib & 1ull) conflict = true;
        }
        unsigned long long elig = __ballot(alive && !conflict);
        if (elig == 0ull) break;
        int w = __ffsll((long long)elig) - 1;
        int wi = __shfl(ci, w), wj = __shfl(cj, w);
        if (lane == w) ob[fi] = ca;
        unsigned long long r0, r1;
        rangemask(wi, wj, r0, r1);
        in0 |= r0; in1 |= r1;
        if (wi < 64) s0 |= (1ull << wi); else s1 |= (1ull << (wi - 64));
        alive = alive && (lane > w);
      }
    }
  }
}

extern "C" void kernel_launch(void* const* d_in, const int* in_sizes, int n_in,
                              void* d_out, int out_size, void* d_ws, size_t ws_size,
                              hipStream_t stream) {
  const int*   word_idxs = (const int*)d_in[0];
  const int*   labels    = (const int*)d_in[1];
  const float* word_emb  = (const float*)d_in[2];
  const float* Wih_f = (const float*)d_in[3];
  const float* Whh_f = (const float*)d_in[4];
  const float* bih_f = (const float*)d_in[5];
  const float* bhh_f = (const float*)d_in[6];
  const float* Wih_b = (const float*)d_in[7];
  const float* Whh_b = (const float*)d_in[8];
  const float* bih_b = (const float*)d_in[9];
  const float* bhh_b = (const float*)d_in[10];
  const float* W_start = (const float*)d_in[11];
  const float* b_start = (const float*)d_in[12];
  const float* W_end   = (const float*)d_in[13];
  const float* b_end   = (const float*)d_in[14];
  const float* W_bi    = (const float*)d_in[15];

  char* ws = (char*)d_ws;
  float* x    = (float*)(ws + OFF_X);
  double* hbuf = (double*)(ws + OFF_HBUF);
  unsigned* flags = (unsigned*)(ws + OFF_FLG);
  float* XWt  = (float*)(ws + OFF_XW);
  float* he   = (float*)(ws + OFF_HE);
  float* enc  = (float*)(ws + OFF_ENC);
  float* U    = (float*)(ws + OFF_U);
  float* x1   = (float*)(ws + OFF_X1);
  float* y1T  = (float*)(ws + OFF_Y1T);
  float* Wbp  = (float*)(ws + OFF_WBP);
  unsigned long long* keys = (unsigned long long*)(ws + OFF_KEYS);
  int* outp = (int*)d_out;

  // 1. embedding gather
  k_gather<<<4096, 256, 0, stream>>>(word_idxs, word_emb, x);
  // 2. input-gate GEMMs, bias folded, stored coalesced as XWt[d][l][b][1600]
  dim3 g2(64, 25);
  k_gemm_nt<<<g2, 256, 0, stream>>>(x, EMBD, Wih_f, EMBD, bih_f, bhh_f,
                                    XWt, 0, 4096, G4, EMBD, 2);
  k_gemm_nt<<<g2, 256, 0, stream>>>(x, EMBD, Wih_b, EMBD, bih_b, bhh_b,
                                    XWt + (size_t)SEQL * 32 * G4, 0, 4096, G4, EMBD, 2);
  // 3. flags zero (x region now dead), then persistent LSTM (flag-synced)
  hipMemsetAsync(ws + OFF_FLG, 0, 4096, stream);
  k_lstm3<<<NBLK, 256, 0, stream>>>(XWt, Whh_f, Whh_b, word_idxs, hbuf, flags, enc);
  // 4. projections: x1 (coalesced) and he (coalesced) -> y1T via LDS transpose
  dim3 g4(64, 8);
  k_gemm_nt<<<g4, 256, 0, stream>>>(enc, 800, W_start, 800, b_start, nullptr,
                                    x1, 516, 4096, FF, 800, 0);
  k_gemm_nt<<<g4, 256, 0, stream>>>(enc, 800, W_end, 800, b_end, nullptr,
                                    he, 512, 4096, FF, 800, 0);
  dim3 gt(16, 4, 32);
  k_y1t<<<gt, 256, 0, stream>>>(he, y1T);
  k_ones<<<32, 256, 0, stream>>>(x1, y1T);
  // 5. biaffine stage 1: U[b,x][o][j] = sum_i x1[b,x,i] W[o,i,j]
  k_wbpad<<<(9 * 513 * 516 + 255) / 256, 256, 0, stream>>>(W_bi, Wbp);
  dim3 g5(64, 9, 9);
  k_gemm_nn<<<g5, 256, 0, stream>>>(x1, 516, Wbp, 516, (size_t)513 * 516,
                                    U, 4644, 4096, 513, 513);
  // 6. stage 2 + argmax + key build
  k_stage2<<<4096, 128, 0, stream>>>(U, y1T, labels, keys);
  // 7. sort + greedy NMS decode
  k_decode<<<32, 1024, 65536, stream>>>(keys, outp);
}

// Round 3
// 2725.429 us; speedup vs baseline: 2.2730x; 1.4758x over previous
//
#include <hip/hip_runtime.h>
#include <math.h>

// Problem constants
#define SEQL 128
#define NB   32
#define EMBD 300
#define HH   400      // hidden per direction
#define G4   1600     // 4*HH
#define FF   512
#define NLAB 9
#define NBLK 200      // persistent LSTM blocks: 2 dirs x 100 slices (4 hidden units each)

// ---------------- workspace layout (bytes) ----------------
static const size_t OFF_X    = 0;          // x [4096][300] f32 — dead after input GEMMs
static const size_t OFF_HBUF = 0;          // h double-buffer [2][2][400][32] f64 (819,200) — live only in k_lstm3
static const size_t OFF_FLG  = 1048576;    // publish flags [2][128] u32 — in dead x region
static const size_t OFF_XW   = 5242880;    // XWt [2][128][32][1600] f32 (52,428,800) dead after LSTM; he reuses it
static const size_t OFF_HE   = 5242880;    // he [4096][512] f32 (8,388,608) — after LSTM, before gemm_nn
static const size_t OFF_ENC  = 62914560;   // enc [4096][800] f32 (13,107,200) dead after proj GEMMs
static const size_t OFF_U    = 0;          // U [4096][9][516] f32 (76,087,296) overlays all of the above post-proj
static const size_t OFF_X1   = 76087296;   // x1 [4096][516] (8,454,144)
static const size_t OFF_Y1T  = 84541440;   // y1T [32][513][128] (8,404,992)
static const size_t OFF_KEYS = 92946432;   // keys u64 [32][16384] (4,194,304)
static const size_t OFF_WBP  = 97140736;   // Wb padded [9][513][516] (9,529,488)

// ---------------- agent-scope (IF-coherent, cache-bypassing) accessors ----------------
__device__ __forceinline__ double aload(const double* p) {
  return __hip_atomic_load(p, __ATOMIC_RELAXED, __HIP_MEMORY_SCOPE_AGENT);
}
__device__ __forceinline__ void astore(double* p, double v) {
  __hip_atomic_store(p, v, __ATOMIC_RELAXED, __HIP_MEMORY_SCOPE_AGENT);
}
__device__ __forceinline__ unsigned afload(const unsigned* p) {
  return __hip_atomic_load(p, __ATOMIC_RELAXED, __HIP_MEMORY_SCOPE_AGENT);
}
__device__ __forceinline__ void afstore(unsigned* p, unsigned v) {
  __hip_atomic_store(p, v, __ATOMIC_RELAXED, __HIP_MEMORY_SCOPE_AGENT);
}

// ---------------- embedding gather ----------------
__global__ __launch_bounds__(256) void k_gather(const int* __restrict__ wi,
                                                const float* __restrict__ emb,
                                                float* __restrict__ x) {
  int m = blockIdx.x;
  int idx = wi[m];
  const float* src = emb + (size_t)idx * EMBD;
  float* dst = x + (size_t)m * EMBD;
  for (int e = threadIdx.x; e < EMBD; e += 256) dst[e] = src[e];
}

// ---------------- W_biaffine pad to stride 516 ----------------
__global__ __launch_bounds__(256) void k_wbpad(const float* __restrict__ wbi,
                                               float* __restrict__ wbp) {
  int tid = blockIdx.x * 256 + threadIdx.x;
  const int PER = 513 * 516;
  if (tid >= 9 * PER) return;
  int o = tid / PER;
  int r = tid - o * PER;
  int i = r / 516;
  int j = r - i * 516;
  wbp[tid] = (j < 513) ? wbi[(size_t)o * 513 * 513 + (size_t)i * 513 + j] : 0.f;
}

// ---------------- ones columns ----------------
__global__ __launch_bounds__(256) void k_ones(float* __restrict__ x1, float* __restrict__ y1T) {
  int tid = blockIdx.x * 256 + threadIdx.x;
  if (tid < 4096) {
    x1[(size_t)tid * 516 + 512] = 1.f;
  } else if (tid < 8192) {
    int r = tid - 4096;
    int bb = r >> 7, y = r & 127;
    y1T[((size_t)bb * 513 + 512) * 128 + y] = 1.f;
  }
}

// ---------------- he -> y1T transpose (coalesced both sides) ----------------
__global__ __launch_bounds__(256) void k_y1t(const float* __restrict__ he,
                                             float* __restrict__ y1T) {
  __shared__ float tile[32][33];
  int b = blockIdx.z;
  int n0 = blockIdx.x * 32, y0 = blockIdx.y * 32;
  int tx = threadIdx.x & 31, ty = threadIdx.x >> 5;
  for (int yy = ty; yy < 32; yy += 8)
    tile[yy][tx] = he[((size_t)b * 128 + y0 + yy) * 512 + n0 + tx];
  __syncthreads();
  for (int nn = ty; nn < 32; nn += 8)
    y1T[((size_t)b * 513 + n0 + nn) * 128 + y0 + tx] = tile[tx][nn];
}

// ---------------- tiled GEMM, f64 accumulate, f32 LDS staging (exact: cvt after read)
// mode 0: normal store (ldc); mode 2: XWt store [l][b][n] (coalesced)
__global__ __launch_bounds__(256) void k_gemm_nt(const float* __restrict__ A, int lda,
                                                 const float* __restrict__ W, int ldw,
                                                 const float* __restrict__ bias1,
                                                 const float* __restrict__ bias2,
                                                 float* __restrict__ C, int ldc,
                                                 int M, int N, int K, int mode) {
  __shared__ __align__(16) float As[16][68];
  __shared__ __align__(16) float Bs[16][68];
  int t = threadIdx.x;
  int m0 = blockIdx.x * 64, n0 = blockIdx.y * 64;
  int tm = t & 15, tn = t >> 4;
  int ar = t >> 2, akq = t & 3;
  double acc[4][4];
#pragma unroll
  for (int r = 0; r < 4; ++r)
#pragma unroll
    for (int c = 0; c < 4; ++c) acc[r][c] = 0.0;

  for (int k0 = 0; k0 < K; k0 += 16) {
    {
      const float* ap = A + (size_t)(m0 + ar) * lda + k0 + 4 * akq;
      float v0, v1, v2, v3;
      if (k0 + 4 * akq + 4 <= K) {
        float4 f = *(const float4*)ap; v0 = f.x; v1 = f.y; v2 = f.z; v3 = f.w;
      } else {
        v0 = (k0 + 4 * akq + 0 < K) ? ap[0] : 0.f;
        v1 = (k0 + 4 * akq + 1 < K) ? ap[1] : 0.f;
        v2 = (k0 + 4 * akq + 2 < K) ? ap[2] : 0.f;
        v3 = (k0 + 4 * akq + 3 < K) ? ap[3] : 0.f;
      }
      As[4 * akq + 0][ar] = v0; As[4 * akq + 1][ar] = v1;
      As[4 * akq + 2][ar] = v2; As[4 * akq + 3][ar] = v3;
    }
    {
      int nr = n0 + ar;
      float v0 = 0.f, v1 = 0.f, v2 = 0.f, v3 = 0.f;
      if (nr < N) {
        const float* wp = W + (size_t)nr * ldw + k0 + 4 * akq;
        if (k0 + 4 * akq + 4 <= K) {
          float4 f = *(const float4*)wp; v0 = f.x; v1 = f.y; v2 = f.z; v3 = f.w;
        } else {
          if (k0 + 4 * akq + 0 < K) v0 = wp[0];
          if (k0 + 4 * akq + 1 < K) v1 = wp[1];
          if (k0 + 4 * akq + 2 < K) v2 = wp[2];
          if (k0 + 4 * akq + 3 < K) v3 = wp[3];
        }
      }
      Bs[4 * akq + 0][ar] = v0; Bs[4 * akq + 1][ar] = v1;
      Bs[4 * akq + 2][ar] = v2; Bs[4 * akq + 3][ar] = v3;
    }
    __syncthreads();
#pragma unroll
    for (int kk = 0; kk < 16; ++kk) {
      float4 a4 = *(const float4*)&As[kk][4 * tm];
      float4 b4 = *(const float4*)&Bs[kk][4 * tn];
      double av[4] = {(double)a4.x, (double)a4.y, (double)a4.z, (double)a4.w};
      double bv[4] = {(double)b4.x, (double)b4.y, (double)b4.z, (double)b4.w};
#pragma unroll
      for (int r = 0; r < 4; ++r)
#pragma unroll
        for (int c = 0; c < 4; ++c) acc[r][c] = fma(av[r], bv[c], acc[r][c]);
    }
    __syncthreads();
  }
  double bn[4];
#pragma unroll
  for (int c = 0; c < 4; ++c) {
    int n = n0 + 4 * tn + c;
    double bv = 0.0;
    if (n < N) {
      if (bias1) bv += (double)bias1[n];
      if (bias2) bv += (double)bias2[n];
    }
    bn[c] = bv;
  }
  if (mode == 0) {
#pragma unroll
    for (int r = 0; r < 4; ++r) {
      int m = m0 + 4 * tm + r;
      float* cp = C + (size_t)m * ldc + n0 + 4 * tn;
      if (n0 + 4 * tn + 4 <= N) {
        float4 s = make_float4((float)(acc[r][0] + bn[0]), (float)(acc[r][1] + bn[1]),
                               (float)(acc[r][2] + bn[2]), (float)(acc[r][3] + bn[3]));
        *(float4*)cp = s;
      } else {
#pragma unroll
        for (int c = 0; c < 4; ++c)
          if (n0 + 4 * tn + c < N) cp[c] = (float)(acc[r][c] + bn[c]);
      }
    }
  } else {
    // XWt store: row = l*32 + b (m = b*128 + l), coalesced float4 in n
#pragma unroll
    for (int r = 0; r < 4; ++r) {
      int m = m0 + 4 * tm + r;
      int bb = m >> 7, l = m & 127;
      float* cp = C + ((size_t)l * 32 + bb) * G4 + n0 + 4 * tn;
      float4 s = make_float4((float)(acc[r][0] + bn[0]), (float)(acc[r][1] + bn[1]),
                             (float)(acc[r][2] + bn[2]), (float)(acc[r][3] + bn[3]));
      *(float4*)cp = s;
    }
  }
}

// ---------------- tiled GEMM f64-acc, f32 LDS staging, batched over o ----------------
__global__ __launch_bounds__(256) void k_gemm_nn(const float* __restrict__ A, int lda,
                                                 const float* __restrict__ Bm, int ldb,
                                                 size_t strideB,
                                                 float* __restrict__ C, int ldc,
                                                 int M, int N, int K) {
  __shared__ __align__(16) float As[16][68];
  __shared__ __align__(16) float Bs[16][68];
  int t = threadIdx.x;
  int o = blockIdx.z;
  const float* B = Bm + (size_t)o * strideB;
  float* Cb = C + (size_t)o * 516;
  int m0 = blockIdx.x * 64, n0 = blockIdx.y * 64;
  int tm = t & 15, tn = t >> 4;
  int ar = t >> 2, akq = t & 3;
  double acc[4][4];
#pragma unroll
  for (int r = 0; r < 4; ++r)
#pragma unroll
    for (int c = 0; c < 4; ++c) acc[r][c] = 0.0;

  for (int k0 = 0; k0 < K; k0 += 16) {
    {
      const float* ap = A + (size_t)(m0 + ar) * lda + k0 + 4 * akq;
      float v0, v1, v2, v3;
      if (k0 + 4 * akq + 4 <= K) {
        float4 f = *(const float4*)ap; v0 = f.x; v1 = f.y; v2 = f.z; v3 = f.w;
      } else {
        v0 = (k0 + 4 * akq + 0 < K) ? ap[0] : 0.f;
        v1 = (k0 + 4 * akq + 1 < K) ? ap[1] : 0.f;
        v2 = (k0 + 4 * akq + 2 < K) ? ap[2] : 0.f;
        v3 = (k0 + 4 * akq + 3 < K) ? ap[3] : 0.f;
      }
      As[4 * akq + 0][ar] = v0; As[4 * akq + 1][ar] = v1;
      As[4 * akq + 2][ar] = v2; As[4 * akq + 3][ar] = v3;
    }
    {
      int kr = k0 + (t >> 4);
      int nc = n0 + 4 * (t & 15);
      float v0 = 0.f, v1 = 0.f, v2 = 0.f, v3 = 0.f;
      if (kr < K) {
        const float* bp = B + (size_t)kr * ldb + nc;
        if (nc + 4 <= N) {
          float4 f = *(const float4*)bp; v0 = f.x; v1 = f.y; v2 = f.z; v3 = f.w;
        } else {
          if (nc + 0 < N) v0 = bp[0];
          if (nc + 1 < N) v1 = bp[1];
          if (nc + 2 < N) v2 = bp[2];
          if (nc + 3 < N) v3 = bp[3];
        }
      }
      int kk = t >> 4, nq = 4 * (t & 15);
      Bs[kk][nq + 0] = v0; Bs[kk][nq + 1] = v1;
      Bs[kk][nq + 2] = v2; Bs[kk][nq + 3] = v3;
    }
    __syncthreads();
#pragma unroll
    for (int kk = 0; kk < 16; ++kk) {
      float4 a4 = *(const float4*)&As[kk][4 * tm];
      float4 b4 = *(const float4*)&Bs[kk][4 * tn];
      double av[4] = {(double)a4.x, (double)a4.y, (double)a4.z, (double)a4.w};
      double bv[4] = {(double)b4.x, (double)b4.y, (double)b4.z, (double)b4.w};
#pragma unroll
      for (int r = 0; r < 4; ++r)
#pragma unroll
        for (int c = 0; c < 4; ++c) acc[r][c] = fma(av[r], bv[c], acc[r][c]);
    }
    __syncthreads();
  }
#pragma unroll
  for (int r = 0; r < 4; ++r) {
    int m = m0 + 4 * tm + r;
    float* cp = Cb + (size_t)m * ldc + n0 + 4 * tn;
    if (n0 + 4 * tn + 4 <= N) {
      *(float4*)cp = make_float4((float)acc[r][0], (float)acc[r][1],
                                 (float)acc[r][2], (float)acc[r][3]);
    } else {
#pragma unroll
      for (int c = 0; c < 4; ++c)
        if (n0 + 4 * tn + c < N) cp[c] = (float)acc[r][c];
    }
  }
}

// ---------------- persistent BiLSTM v5: MLP-staged h tile + conflict-free inner reads
__global__ __launch_bounds__(256, 1) void k_lstm3(const float* __restrict__ xwt,   // [2][128][32][1600] f32
                                                  const float* __restrict__ whh_f, // [1600][400]
                                                  const float* __restrict__ whh_b,
                                                  const int* __restrict__ word_idxs,
                                                  double* __restrict__ hbuf,       // [2][2][400][32] f64
                                                  unsigned* __restrict__ flags,    // [2][128] u32
                                                  float* __restrict__ enc) {
  __shared__ __align__(16) double Wvd[4 * 400 * 4];   // [u][k][g] f64, 51,200 B
  __shared__ __align__(16) double Shd[12800];          // h tile [k 0..399][b 0..31], 102,400 B
  int bid = blockIdx.x;
  int d = bid / 100, slice = bid - d * 100;
  const float* whh = d ? whh_b : whh_f;
  const float* xwd = xwt + (size_t)d * SEQL * 32 * G4;
  unsigned* flg = flags + (size_t)d * 128;
  int t = threadIdx.x;

  // one-time: stage Whh rows for our 4 units x 4 gates into LDS as f64 [u][k][g]
  for (int pp = 0; pp < 16; ++pp) {
    int u = pp >> 2, g = pp & 3;
    const float* src = whh + (size_t)(g * 400 + slice * 4 + u) * 400;
    for (int k = t; k < 400; k += 256) Wvd[((size_t)u * 400 + k) * 4 + g] = (double)src[k];
  }

  int su = t >> 6;          // wave id = unit index within slice (0..3)
  int lane = t & 63;
  int kp = lane >> 4;       // k-phase (0..3) — high lane bits: conflict-free Shd reads
  int p  = lane & 15;       // batch-pair index (0..15)
  int sb2 = 2 * p;
  int kglob = slice * 4 + su;
  int cb = sb2 + kp;        // this thread's batch column (valid for kp<2)
  double cst = 0.0;

  if (kp < 2)
    astore(&hbuf[((size_t)1 * 2 + d) * 12800 + (size_t)kglob * 32 + cb], 0.0);
  __syncthreads();                        // drain vmcnt (h init visible)
  if (t == 0) afstore(&flg[slice], 1u);   // publish #1 (initial h)

  for (int s = 0; s < SEQL; ++s) {
    int l = d ? (SEQL - 1 - s) : s;
    int rp = (s + 1) & 1, wp = s & 1;
    const double* hr = hbuf + ((size_t)rp * 2 + d) * 12800;
    double* hwb = hbuf + ((size_t)wp * 2 + d) * 12800;
    unsigned need = (unsigned)(s + 1);

    // prefetch xw gates + mask for (unit su, batch cb) — consumed at step end (latency hidden)
    float xw0 = 0.f, xw1 = 0.f, xw2 = 0.f, xw3 = 0.f;
    bool m = false;
    if (kp < 2) {
      const float* xp = xwd + ((size_t)l * 32 + cb) * G4 + kglob;
      xw0 = xp[0]; xw1 = xp[400]; xw2 = xp[800]; xw3 = xp[1200];
      m = word_idxs[cb * SEQL + l] > 0;
    }

    // single poll per step: wave su polls producer flags [su*25, su*25+25)
    {
      bool mine = lane < 25;
      const unsigned* fp = flg + su * 25 + lane;
      while (true) {
        unsigned v = mine ? afload(fp) : 0xFFFFFFFFu;
        if (__ballot(v < need) == 0ull) break;
        __builtin_amdgcn_s_sleep(1);
      }
    }
    __syncthreads();   // all 100 flags >= s+1; prior-step Shd consumption done

    // stage the full h tile (400x32 f64): issue ALL 50 loads, then write LDS.
    {
      double r[50];
#pragma unroll
      for (int j = 0; j < 50; ++j) r[j] = aload(&hr[t + 256 * j]);
#pragma unroll
      for (int j = 0; j < 50; ++j) Shd[t + 256 * j] = r[j];
    }
    __syncthreads();

    double acc[8];
#pragma unroll
    for (int z = 0; z < 8; ++z) acc[z] = 0.0;
#pragma unroll 4
    for (int kk = 0; kk < 100; ++kk) {
      int klocal = 4 * kk + kp;
      double2 hp = *(const double2*)&Shd[(size_t)klocal * 32 + sb2];
      const double2* wrow = (const double2*)&Wvd[((size_t)su * 400 + klocal) * 4];
      double2 w01 = wrow[0];   // gates i,f
      double2 w23 = wrow[1];   // gates g,o
      acc[0] = fma(w01.x, hp.x, acc[0]);
      acc[1] = fma(w01.x, hp.y, acc[1]);
      acc[2] = fma(w01.y, hp.x, acc[2]);
      acc[3] = fma(w01.y, hp.y, acc[3]);
      acc[4] = fma(w23.x, hp.x, acc[4]);
      acc[5] = fma(w23.x, hp.y, acc[5]);
      acc[6] = fma(w23.y, hp.x, acc[6]);
      acc[7] = fma(w23.y, hp.y, acc[7]);
    }
    // reduce the 4-way k-split across kp groups (lane bits 4,5)
#pragma unroll
    for (int z = 0; z < 8; ++z) {
      acc[z] += __shfl_xor(acc[z], 16);
      acc[z] += __shfl_xor(acc[z], 32);
    }

    if (kp < 2) {
      double gi = acc[0 + kp] + (double)xw0;
      double gf = acc[2 + kp] + (double)xw1;
      double gg = acc[4 + kp] + (double)xw2;
      double go = acc[6 + kp] + (double)xw3;
      double si = (double)(1.f / (1.f + expf(-(float)gi)));
      double sf = (double)(1.f / (1.f + expf(-(float)gf)));
      double so = (double)(1.f / (1.f + expf(-(float)go)));
      double cn = sf * cst + si * (double)tanhf((float)gg);
      double hn = so * (double)tanhf((float)cn);
      double holdv = Shd[(size_t)kglob * 32 + cb];   // own h from step s-1 (still resident)
      double hv = m ? hn : holdv;
      cst = m ? cn : cst;
      astore(&hwb[(size_t)kglob * 32 + cb], hv);
      enc[((size_t)cb * SEQL + l) * 800 + d * 400 + kglob] = m ? (float)hn : 0.f;
    }
    __syncthreads();                          // drain vmcnt: h stores visible
    if (t == 0) afstore(&flg[slice], (unsigned)(s + 2));   // publish
  }
}

// ---------------- stage 2: score + argmax per (b,x), emits sort keys ----------------
__global__ __launch_bounds__(128) void k_stage2(const float* __restrict__ U,
                                                const float* __restrict__ y1T,
                                                const int* __restrict__ labels,
                                                unsigned long long* __restrict__ keys) {
  __shared__ double Ur[4644];
  int bx = blockIdx.x;
  int b = bx >> 7, x = bx & 127;
  const float* Urow = U + (size_t)bx * 4644;
  for (int i = threadIdx.x; i < 4644; i += 128) Ur[i] = (double)Urow[i];
  __syncthreads();
  int y = threadIdx.x;
  double acc[9];
#pragma unroll
  for (int o = 0; o < 9; ++o) acc[o] = 0.0;
  const float* yb = y1T + (size_t)b * 513 * 128 + y;
  for (int j = 0; j < 513; ++j) {
    double yv = (double)yb[(size_t)j * 128];
#pragma unroll
    for (int o = 0; o < 9; ++o) acc[o] = fma(Ur[o * 516 + j], yv, acc[o]);
  }
  double best = acc[0];
  int bi = 0;
#pragma unroll
  for (int o = 1; o < 9; ++o) {
    if (acc[o] > best) { best = acc[o]; bi = o; }
  }
  int fi = x * 128 + y;
  int lab = labels[(size_t)bx * 128 + y];
  bool valid = (bi != 1) && (lab > 0);
  unsigned long long key;
  if (valid) {
    unsigned long long u = (unsigned long long)__double_as_longlong(best);
    unsigned long long mm = (u >> 63) ? ~u : (u | 0x8000000000000000ull);
    unsigned long long dm = ~mm;
    key = (dm & ~0x3FFFFull) | ((unsigned long long)(unsigned)fi << 4) |
          (unsigned long long)(unsigned)bi;
  } else {
    key = ~0ull;
  }
  keys[(size_t)b * 16384 + fi] = key;
}

// ---------------- decode phase 1: sort 2048-key chunks (8 per sentence, 256 blocks total)
// Also initializes the output to NON_ENTITY=1 (coalesced, spread across all blocks).
__global__ __launch_bounds__(256) void k_sortchunks(unsigned long long* __restrict__ keysg,
                                                    int* __restrict__ outp) {
  __shared__ unsigned long long s[2048];
  int c = blockIdx.x, b = blockIdx.y;
  unsigned long long* kg = keysg + (size_t)b * 16384 + (size_t)c * 2048;
  int* ob = outp + (size_t)b * 16384 + (size_t)c * 2048;
  int t = threadIdx.x;
  for (int i = t; i < 2048; i += 256) s[i] = kg[i];
  for (int i = t; i < 2048; i += 256) ob[i] = 1;
  __syncthreads();
  for (int k = 2; k <= 2048; k <<= 1) {
    for (int j = k >> 1; j > 0; j >>= 1) {
#pragma unroll
      for (int p = 0; p < 4; ++p) {
        int ii = p * 256 + t;                       // compare index 0..1023
        int i = ((ii & ~(j - 1)) << 1) | (ii & (j - 1));
        int ix = i | j;
        bool up = ((i & k) == 0);
        unsigned long long a = s[i], bb = s[ix];
        if (up ? (a > bb) : (a < bb)) { s[i] = bb; s[ix] = a; }
      }
      __syncthreads();
    }
  }
  for (int i = t; i < 2048; i += 256) kg[i] = s[i];
}

// ---------------- decode phase 2: per-sentence merge 8x2048 -> 16384 (ascending) ----------------
__global__ __launch_bounds__(1024) void k_merge8(unsigned long long* __restrict__ keysg) {
  extern __shared__ unsigned long long m[];   // 8192 u64 = 64 KB
  int b = blockIdx.x;
  int t = threadIdx.x;
  unsigned long long* kg = keysg + (size_t)b * 16384;

  // Round A: merge pairs of 2048-runs -> 4096-runs (two pairs per pass, both ascending)
  for (int pass = 0; pass < 2; ++pass) {
    unsigned long long* base = kg + (size_t)pass * 8192;
    for (int i = t; i < 2048; i += 1024) {
      m[i]        = base[i];                    // run0 fwd
      m[2048 + i] = base[2048 + 2047 - i];      // run1 rev -> bitonic block 0
      m[4096 + i] = base[4096 + i];             // run2 fwd
      m[6144 + i] = base[6144 + 2047 - i];      // run3 rev -> bitonic block 1
    }
    __syncthreads();
    for (int j = 2048; j > 0; j >>= 1) {
#pragma unroll
      for (int p = 0; p < 4; ++p) {
        int ii = p * 1024 + t;                  // compare idx 0..4095 over 8192 elems
        int i = ((ii & ~(j - 1)) << 1) | (ii & (j - 1));
        int ix = i | j;
        unsigned long long a = m[i], c = m[ix];
        if (a > c) { m[i] = c; m[ix] = a; }     // ascending in both 4096-blocks
      }
      __syncthreads();
    }
    for (int i = t; i < 8192; i += 1024) base[i] = m[i];
    __syncthreads();
  }

  // Round B: merge 4096+4096 -> 8192; half 0 ascending, half 1 DESCENDING (sets up round C)
  for (int pass = 0; pass < 2; ++pass) {
    unsigned long long* base = kg + (size_t)pass * 8192;
    for (int i = t; i < 4096; i += 1024) {
      m[i]        = base[i];                    // fwd
      m[4096 + i] = base[4096 + 4095 - i];      // rev -> bitonic 8192
    }
    __syncthreads();
    bool desc = (pass == 1);
    for (int j = 4096; j > 0; j >>= 1) {
#pragma unroll
      for (int p = 0; p < 4; ++p) {
        int ii = p * 1024 + t;                  // compare idx 0..4095
        int i = ((ii & ~(j - 1)) << 1) | (ii & (j - 1));
        int ix = i | j;
        unsigned long long a = m[i], c = m[ix];
        if (desc ? (a < c) : (a > c)) { m[i] = c; m[ix] = a; }
      }
      __syncthreads();
    }
    for (int i = t; i < 8192; i += 1024) base[i] = m[i];
    __syncthreads();
  }

  // Round C: asc ++ desc = bitonic 16384. Global stage j=8192, then two 8192 LDS asc merges.
  for (int i = t; i < 8192; i += 1024) {
    unsigned long long a = kg[i], c = kg[i + 8192];
    if (a > c) { kg[i] = c; kg[i + 8192] = a; }
  }
  __syncthreads();
  for (int half = 0; half < 2; ++half) {
    unsigned long long* base = kg + (size_t)half * 8192;
    for (int i = t; i < 8192; i += 1024) m[i] = base[i];
    __syncthreads();
    for (int j = 4096; j > 0; j >>= 1) {
#pragma unroll
      for (int p = 0; p < 4; ++p) {
        int ii = p * 1024 + t;
        int i = ((ii & ~(j - 1)) << 1) | (ii & (j - 1));
        int ix = i | j;
        unsigned long long a = m[i], c = m[ix];
        if (a > c) { m[i] = c; m[ix] = a; }
      }
      __syncthreads();
    }
    for (int i = t; i < 8192; i += 1024) base[i] = m[i];
    __syncthreads();
  }
}

// ---------------- decode helpers ----------------
__device__ __forceinline__ void rangemask(int i, int j,
                                          unsigned long long& r0, unsigned long long& r1) {
  if (i > j) { r0 = 0ull; r1 = 0ull; return; }
  unsigned long long u0, u1;
  if (j >= 64) { u0 = ~0ull; u1 = (j >= 127) ? ~0ull : ((1ull << (j - 63)) - 1ull); }
  else         { u0 = (j == 63) ? ~0ull : ((1ull << (j + 1)) - 1ull); u1 = 0ull; }
  unsigned long long f0, f1;
  if (i >= 64) { f0 = 0ull; f1 = (~0ull) << (i - 64); }
  else         { f0 = (~0ull) << i; f1 = ~0ull; }
  r0 = u0 & f0; r1 = u1 & f1;
}

// ---------------- decode phase 3: batched greedy NMS scan (decision-equivalent to serial)
// Conflict is MONOTONE (start/inside bits only grow), so per 64-candidate chunk:
//   (1) reject all currently-conflicting candidates en masse (they can never accept later);
//   (2) point candidates (i>j) before the first surviving range candidate depend only on
//       `inside` (unchanged until a range accept) -> accept all in parallel, OR their
//       start bits (which later range candidates' cnt must see);
//   (3) decide the single range candidate against the updated starts; loop.
// Serial events = surviving range candidates only (vs one per accept in the old loop).
__global__ __launch_bounds__(64) void k_scan(const unsigned long long* __restrict__ keysg,
                                             int* __restrict__ outp) {
  int b = blockIdx.x;
  int lane = threadIdx.x;
  const unsigned long long* kg = keysg + (size_t)b * 16384;
  int* ob = outp + (size_t)b * 16384;
  unsigned long long s0 = 0, s1 = 0, in0 = 0, in1 = 0;

  for (int base = 0; base < 16384; base += 64) {
    unsigned long long key = kg[base + lane];
    bool valid = (key != ~0ull);
    if (__ballot(valid) == 0ull) break;          // keys ascending: rest invalid too
    int fi = (int)((key >> 4) & 0x3FFFull);
    int ci = fi >> 7, cj = fi & 127, ca = (int)(key & 15ull);
    bool isR = (ci <= cj);
    unsigned long long r0, r1; rangemask(ci, cj, r0, r1);
    unsigned long long rangeB = __ballot(isR);
    unsigned long long unp = __ballot(valid);

    while (unp) {
      bool insb = (((ci < 64) ? (in0 >> ci) : (in1 >> (ci - 64))) & 1ull) != 0;
      bool ovl = ((r0 & s0) | (r1 & s1)) != 0ull;
      bool myc = insb || (isR && ovl);
      unsigned long long confl = __ballot(myc);
      unp &= ~confl;                              // monotone -> permanent reject
      if (!unp) break;
      unsigned long long er = unp & rangeB;
      if (er == 0ull) {
        // all remaining are non-conflicting points: accept all, update starts, done
        if ((unp >> lane) & 1ull) ob[fi] = ca;
        unsigned long long c0 = 0, c1 = 0;
        if ((unp >> lane) & 1ull) { if (ci < 64) c0 = 1ull << ci; else c1 = 1ull << (ci - 64); }
#pragma unroll
        for (int off = 32; off; off >>= 1) { c0 |= __shfl_xor(c0, off); c1 |= __shfl_xor(c1, off); }
        s0 |= c0; s1 |= c1;
        break;
      }
      int r = __ffsll((long long)er) - 1;
      unsigned long long below = (r == 0) ? 0ull : ((1ull << r) - 1ull);
      unsigned long long pb = unp & below;        // all points (earlier ranges rejected/processed)
      if (pb) {
        if ((pb >> lane) & 1ull) ob[fi] = ca;
        unsigned long long c0 = 0, c1 = 0;
        if ((pb >> lane) & 1ull) { if (ci < 64) c0 = 1ull << ci; else c1 = 1ull << (ci - 64); }
#pragma unroll
        for (int off = 32; off; off >>= 1) { c0 |= __shfl_xor(c0, off); c1 |= __shfl_xor(c1, off); }
        s0 |= c0; s1 |= c1;
        unp &= ~pb;
      }
      // decide range candidate r against the updated starts
      int wi = __shfl(ci, r), wj = __shfl(cj, r), wa = __shfl(ca, r), wfi = __shfl(fi, r);
      unsigned long long rr0, rr1; rangemask(wi, wj, rr0, rr1);
      bool rin = (((wi < 64) ? (in0 >> wi) : (in1 >> (wi - 64))) & 1ull) != 0;
      bool rovl = ((rr0 & s0) | (rr1 & s1)) != 0ull;
      if (!(rin || rovl)) {
        if (lane == r) ob[wfi] = wa;
        if (wi < 64) s0 |= 1ull << wi; else s1 |= 1ull << (wi - 64);
        in0 |= rr0; in1 |= rr1;
      }
      unp &= ~(1ull << r);
    }
  }
}

extern "C" void kernel_launch(void* const* d_in, const int* in_sizes, int n_in,
                              void* d_out, int out_size, void* d_ws, size_t ws_size,
                              hipStream_t stream) {
  const int*   word_idxs = (const int*)d_in[0];
  const int*   labels    = (const int*)d_in[1];
  const float* word_emb  = (const float*)d_in[2];
  const float* Wih_f = (const float*)d_in[3];
  const float* Whh_f = (const float*)d_in[4];
  const float* bih_f = (const float*)d_in[5];
  const float* bhh_f = (const float*)d_in[6];
  const float* Wih_b = (const float*)d_in[7];
  const float* Whh_b = (const float*)d_in[8];
  const float* bih_b = (const float*)d_in[9];
  const float* bhh_b = (const float*)d_in[10];
  const float* W_start = (const float*)d_in[11];
  const float* b_start = (const float*)d_in[12];
  const float* W_end   = (const float*)d_in[13];
  const float* b_end   = (const float*)d_in[14];
  const float* W_bi    = (const float*)d_in[15];

  char* ws = (char*)d_ws;
  float* x    = (float*)(ws + OFF_X);
  double* hbuf = (double*)(ws + OFF_HBUF);
  unsigned* flags = (unsigned*)(ws + OFF_FLG);
  float* XWt  = (float*)(ws + OFF_XW);
  float* he   = (float*)(ws + OFF_HE);
  float* enc  = (float*)(ws + OFF_ENC);
  float* U    = (float*)(ws + OFF_U);
  float* x1   = (float*)(ws + OFF_X1);
  float* y1T  = (float*)(ws + OFF_Y1T);
  float* Wbp  = (float*)(ws + OFF_WBP);
  unsigned long long* keys = (unsigned long long*)(ws + OFF_KEYS);
  int* outp = (int*)d_out;

  // 1. embedding gather
  k_gather<<<4096, 256, 0, stream>>>(word_idxs, word_emb, x);
  // 2. input-gate GEMMs, bias folded, stored coalesced as XWt[d][l][b][1600]
  dim3 g2(64, 25);
  k_gemm_nt<<<g2, 256, 0, stream>>>(x, EMBD, Wih_f, EMBD, bih_f, bhh_f,
                                    XWt, 0, 4096, G4, EMBD, 2);
  k_gemm_nt<<<g2, 256, 0, stream>>>(x, EMBD, Wih_b, EMBD, bih_b, bhh_b,
                                    XWt + (size_t)SEQL * 32 * G4, 0, 4096, G4, EMBD, 2);
  // 3. flags zero (x region now dead), then persistent LSTM (flag-synced)
  hipMemsetAsync(ws + OFF_FLG, 0, 4096, stream);
  k_lstm3<<<NBLK, 256, 0, stream>>>(XWt, Whh_f, Whh_b, word_idxs, hbuf, flags, enc);
  // 4. projections: x1 (coalesced) and he (coalesced) -> y1T via LDS transpose
  dim3 g4(64, 8);
  k_gemm_nt<<<g4, 256, 0, stream>>>(enc, 800, W_start, 800, b_start, nullptr,
                                    x1, 516, 4096, FF, 800, 0);
  k_gemm_nt<<<g4, 256, 0, stream>>>(enc, 800, W_end, 800, b_end, nullptr,
                                    he, 512, 4096, FF, 800, 0);
  dim3 gt(16, 4, 32);
  k_y1t<<<gt, 256, 0, stream>>>(he, y1T);
  k_ones<<<32, 256, 0, stream>>>(x1, y1T);
  // 5. biaffine stage 1: U[b,x][o][j] = sum_i x1[b,x,i] W[o,i,j]
  k_wbpad<<<(9 * 513 * 516 + 255) / 256, 256, 0, stream>>>(W_bi, Wbp);
  dim3 g5(64, 9, 9);
  k_gemm_nn<<<g5, 256, 0, stream>>>(x1, 516, Wbp, 516, (size_t)513 * 516,
                                    U, 4644, 4096, 513, 513);
  // 6. stage 2 + argmax + key build
  k_stage2<<<4096, 128, 0, stream>>>(U, y1T, labels, keys);
  // 7. decode: chunk sort (full GPU) -> per-sentence merge -> batched NMS scan
  dim3 gs(8, 32);
  k_sortchunks<<<gs, 256, 0, stream>>>(keys, outp);
  k_merge8<<<32, 1024, 65536, stream>>>(keys);
  k_scan<<<32, 64, 0, stream>>>(keys, outp);
}

// Round 4
// 2618.119 us; speedup vs baseline: 2.3662x; 1.0410x over previous
//
#include <hip/hip_runtime.h>
#include <math.h>

// Problem constants
#define SEQL 128
#define NB   32
#define EMBD 300
#define HH   400      // hidden per direction
#define G4   1600     // 4*HH
#define FF   512
#define NLAB 9
#define NBLK 200      // persistent LSTM blocks: 2 dirs x 100 slices (4 hidden units each)

// ---------------- workspace layout (bytes) ----------------
static const size_t OFF_X    = 0;          // x [4096][300] f32 — dead after input GEMMs
static const size_t OFF_HBUF = 0;          // h double-buffer [2][2][400][32] f32 (204,800) — live only in k_lstm3
static const size_t OFF_FLG  = 1048576;    // publish flags [2][128] u32 — in dead x region
static const size_t OFF_XW   = 5242880;    // XWt [2][128][32][1600] f32 (52,428,800) dead after LSTM; he reuses it
static const size_t OFF_HE   = 5242880;    // he [4096][512] f32 (8,388,608) — after LSTM, before gemm_nn
static const size_t OFF_ENC  = 62914560;   // enc [4096][800] f32 (13,107,200) dead after proj GEMMs
static const size_t OFF_U    = 0;          // U [4096][9][516] f32 (76,087,296) overlays all of the above post-proj
static const size_t OFF_X1   = 76087296;   // x1 [4096][516] (8,454,144)
static const size_t OFF_Y1T  = 84541440;   // y1T [32][513][128] (8,404,992)
static const size_t OFF_KEYS = 92946432;   // keys u64 [32][16384] (4,194,304)
static const size_t OFF_WBP  = 97140736;   // Wb padded [9][513][516] (9,529,488)

// ---------------- agent-scope (IF-coherent, cache-bypassing) accessors ----------------
__device__ __forceinline__ float2 aload2f(const float2* p) {
  unsigned long long v = __hip_atomic_load((const unsigned long long*)p,
                                           __ATOMIC_RELAXED, __HIP_MEMORY_SCOPE_AGENT);
  union { unsigned long long u; float2 f; } c; c.u = v; return c.f;
}
__device__ __forceinline__ void astoref(float* p, float v) {
  __hip_atomic_store(p, v, __ATOMIC_RELAXED, __HIP_MEMORY_SCOPE_AGENT);
}
__device__ __forceinline__ unsigned afload(const unsigned* p) {
  return __hip_atomic_load(p, __ATOMIC_RELAXED, __HIP_MEMORY_SCOPE_AGENT);
}
__device__ __forceinline__ void afstore(unsigned* p, unsigned v) {
  __hip_atomic_store(p, v, __ATOMIC_RELAXED, __HIP_MEMORY_SCOPE_AGENT);
}

// ---------------- embedding gather ----------------
__global__ __launch_bounds__(256) void k_gather(const int* __restrict__ wi,
                                                const float* __restrict__ emb,
                                                float* __restrict__ x) {
  int m = blockIdx.x;
  int idx = wi[m];
  const float* src = emb + (size_t)idx * EMBD;
  float* dst = x + (size_t)m * EMBD;
  for (int e = threadIdx.x; e < EMBD; e += 256) dst[e] = src[e];
}

// ---------------- W_biaffine pad to stride 516 ----------------
__global__ __launch_bounds__(256) void k_wbpad(const float* __restrict__ wbi,
                                               float* __restrict__ wbp) {
  int tid = blockIdx.x * 256 + threadIdx.x;
  const int PER = 513 * 516;
  if (tid >= 9 * PER) return;
  int o = tid / PER;
  int r = tid - o * PER;
  int i = r / 516;
  int j = r - i * 516;
  wbp[tid] = (j < 513) ? wbi[(size_t)o * 513 * 513 + (size_t)i * 513 + j] : 0.f;
}

// ---------------- ones columns ----------------
__global__ __launch_bounds__(256) void k_ones(float* __restrict__ x1, float* __restrict__ y1T) {
  int tid = blockIdx.x * 256 + threadIdx.x;
  if (tid < 4096) {
    x1[(size_t)tid * 516 + 512] = 1.f;
  } else if (tid < 8192) {
    int r = tid - 4096;
    int bb = r >> 7, y = r & 127;
    y1T[((size_t)bb * 513 + 512) * 128 + y] = 1.f;
  }
}

// ---------------- he -> y1T transpose (coalesced both sides) ----------------
__global__ __launch_bounds__(256) void k_y1t(const float* __restrict__ he,
                                             float* __restrict__ y1T) {
  __shared__ float tile[32][33];
  int b = blockIdx.z;
  int n0 = blockIdx.x * 32, y0 = blockIdx.y * 32;
  int tx = threadIdx.x & 31, ty = threadIdx.x >> 5;
  for (int yy = ty; yy < 32; yy += 8)
    tile[yy][tx] = he[((size_t)b * 128 + y0 + yy) * 512 + n0 + tx];
  __syncthreads();
  for (int nn = ty; nn < 32; nn += 8)
    y1T[((size_t)b * 513 + n0 + nn) * 128 + y0 + tx] = tile[tx][nn];
}

// ---------------- tiled GEMM, f64 accumulate, f32 LDS staging (exact: cvt after read)
// mode 0: normal store (ldc); mode 2: XWt store [l][b][n] (coalesced)
__global__ __launch_bounds__(256) void k_gemm_nt(const float* __restrict__ A, int lda,
                                                 const float* __restrict__ W, int ldw,
                                                 const float* __restrict__ bias1,
                                                 const float* __restrict__ bias2,
                                                 float* __restrict__ C, int ldc,
                                                 int M, int N, int K, int mode) {
  __shared__ __align__(16) float As[16][68];
  __shared__ __align__(16) float Bs[16][68];
  int t = threadIdx.x;
  int m0 = blockIdx.x * 64, n0 = blockIdx.y * 64;
  int tm = t & 15, tn = t >> 4;
  int ar = t >> 2, akq = t & 3;
  double acc[4][4];
#pragma unroll
  for (int r = 0; r < 4; ++r)
#pragma unroll
    for (int c = 0; c < 4; ++c) acc[r][c] = 0.0;

  for (int k0 = 0; k0 < K; k0 += 16) {
    {
      const float* ap = A + (size_t)(m0 + ar) * lda + k0 + 4 * akq;
      float v0, v1, v2, v3;
      if (k0 + 4 * akq + 4 <= K) {
        float4 f = *(const float4*)ap; v0 = f.x; v1 = f.y; v2 = f.z; v3 = f.w;
      } else {
        v0 = (k0 + 4 * akq + 0 < K) ? ap[0] : 0.f;
        v1 = (k0 + 4 * akq + 1 < K) ? ap[1] : 0.f;
        v2 = (k0 + 4 * akq + 2 < K) ? ap[2] : 0.f;
        v3 = (k0 + 4 * akq + 3 < K) ? ap[3] : 0.f;
      }
      As[4 * akq + 0][ar] = v0; As[4 * akq + 1][ar] = v1;
      As[4 * akq + 2][ar] = v2; As[4 * akq + 3][ar] = v3;
    }
    {
      int nr = n0 + ar;
      float v0 = 0.f, v1 = 0.f, v2 = 0.f, v3 = 0.f;
      if (nr < N) {
        const float* wp = W + (size_t)nr * ldw + k0 + 4 * akq;
        if (k0 + 4 * akq + 4 <= K) {
          float4 f = *(const float4*)wp; v0 = f.x; v1 = f.y; v2 = f.z; v3 = f.w;
        } else {
          if (k0 + 4 * akq + 0 < K) v0 = wp[0];
          if (k0 + 4 * akq + 1 < K) v1 = wp[1];
          if (k0 + 4 * akq + 2 < K) v2 = wp[2];
          if (k0 + 4 * akq + 3 < K) v3 = wp[3];
        }
      }
      Bs[4 * akq + 0][ar] = v0; Bs[4 * akq + 1][ar] = v1;
      Bs[4 * akq + 2][ar] = v2; Bs[4 * akq + 3][ar] = v3;
    }
    __syncthreads();
#pragma unroll
    for (int kk = 0; kk < 16; ++kk) {
      float4 a4 = *(const float4*)&As[kk][4 * tm];
      float4 b4 = *(const float4*)&Bs[kk][4 * tn];
      double av[4] = {(double)a4.x, (double)a4.y, (double)a4.z, (double)a4.w};
      double bv[4] = {(double)b4.x, (double)b4.y, (double)b4.z, (double)b4.w};
#pragma unroll
      for (int r = 0; r < 4; ++r)
#pragma unroll
        for (int c = 0; c < 4; ++c) acc[r][c] = fma(av[r], bv[c], acc[r][c]);
    }
    __syncthreads();
  }
  double bn[4];
#pragma unroll
  for (int c = 0; c < 4; ++c) {
    int n = n0 + 4 * tn + c;
    double bv = 0.0;
    if (n < N) {
      if (bias1) bv += (double)bias1[n];
      if (bias2) bv += (double)bias2[n];
    }
    bn[c] = bv;
  }
  if (mode == 0) {
#pragma unroll
    for (int r = 0; r < 4; ++r) {
      int m = m0 + 4 * tm + r;
      float* cp = C + (size_t)m * ldc + n0 + 4 * tn;
      if (n0 + 4 * tn + 4 <= N) {
        float4 s = make_float4((float)(acc[r][0] + bn[0]), (float)(acc[r][1] + bn[1]),
                               (float)(acc[r][2] + bn[2]), (float)(acc[r][3] + bn[3]));
        *(float4*)cp = s;
      } else {
#pragma unroll
        for (int c = 0; c < 4; ++c)
          if (n0 + 4 * tn + c < N) cp[c] = (float)(acc[r][c] + bn[c]);
      }
    }
  } else {
    // XWt store: row = l*32 + b (m = b*128 + l), coalesced float4 in n
#pragma unroll
    for (int r = 0; r < 4; ++r) {
      int m = m0 + 4 * tm + r;
      int bb = m >> 7, l = m & 127;
      float* cp = C + ((size_t)l * 32 + bb) * G4 + n0 + 4 * tn;
      float4 s = make_float4((float)(acc[r][0] + bn[0]), (float)(acc[r][1] + bn[1]),
                             (float)(acc[r][2] + bn[2]), (float)(acc[r][3] + bn[3]));
      *(float4*)cp = s;
    }
  }
}

// ---------------- tiled GEMM f64-acc, f32 LDS staging, batched over o ----------------
__global__ __launch_bounds__(256) void k_gemm_nn(const float* __restrict__ A, int lda,
                                                 const float* __restrict__ Bm, int ldb,
                                                 size_t strideB,
                                                 float* __restrict__ C, int ldc,
                                                 int M, int N, int K) {
  __shared__ __align__(16) float As[16][68];
  __shared__ __align__(16) float Bs[16][68];
  int t = threadIdx.x;
  int o = blockIdx.z;
  const float* B = Bm + (size_t)o * strideB;
  float* Cb = C + (size_t)o * 516;
  int m0 = blockIdx.x * 64, n0 = blockIdx.y * 64;
  int tm = t & 15, tn = t >> 4;
  int ar = t >> 2, akq = t & 3;
  double acc[4][4];
#pragma unroll
  for (int r = 0; r < 4; ++r)
#pragma unroll
    for (int c = 0; c < 4; ++c) acc[r][c] = 0.0;

  for (int k0 = 0; k0 < K; k0 += 16) {
    {
      const float* ap = A + (size_t)(m0 + ar) * lda + k0 + 4 * akq;
      float v0, v1, v2, v3;
      if (k0 + 4 * akq + 4 <= K) {
        float4 f = *(const float4*)ap; v0 = f.x; v1 = f.y; v2 = f.z; v3 = f.w;
      } else {
        v0 = (k0 + 4 * akq + 0 < K) ? ap[0] : 0.f;
        v1 = (k0 + 4 * akq + 1 < K) ? ap[1] : 0.f;
        v2 = (k0 + 4 * akq + 2 < K) ? ap[2] : 0.f;
        v3 = (k0 + 4 * akq + 3 < K) ? ap[3] : 0.f;
      }
      As[4 * akq + 0][ar] = v0; As[4 * akq + 1][ar] = v1;
      As[4 * akq + 2][ar] = v2; As[4 * akq + 3][ar] = v3;
    }
    {
      int kr = k0 + (t >> 4);
      int nc = n0 + 4 * (t & 15);
      float v0 = 0.f, v1 = 0.f, v2 = 0.f, v3 = 0.f;
      if (kr < K) {
        const float* bp = B + (size_t)kr * ldb + nc;
        if (nc + 4 <= N) {
          float4 f = *(const float4*)bp; v0 = f.x; v1 = f.y; v2 = f.z; v3 = f.w;
        } else {
          if (nc + 0 < N) v0 = bp[0];
          if (nc + 1 < N) v1 = bp[1];
          if (nc + 2 < N) v2 = bp[2];
          if (nc + 3 < N) v3 = bp[3];
        }
      }
      int kk = t >> 4, nq = 4 * (t & 15);
      Bs[kk][nq + 0] = v0; Bs[kk][nq + 1] = v1;
      Bs[kk][nq + 2] = v2; Bs[kk][nq + 3] = v3;
    }
    __syncthreads();
#pragma unroll
    for (int kk = 0; kk < 16; ++kk) {
      float4 a4 = *(const float4*)&As[kk][4 * tm];
      float4 b4 = *(const float4*)&Bs[kk][4 * tn];
      double av[4] = {(double)a4.x, (double)a4.y, (double)a4.z, (double)a4.w};
      double bv[4] = {(double)b4.x, (double)b4.y, (double)b4.z, (double)b4.w};
#pragma unroll
      for (int r = 0; r < 4; ++r)
#pragma unroll
        for (int c = 0; c < 4; ++c) acc[r][c] = fma(av[r], bv[c], acc[r][c]);
    }
    __syncthreads();
  }
#pragma unroll
  for (int r = 0; r < 4; ++r) {
    int m = m0 + 4 * tm + r;
    float* cp = Cb + (size_t)m * ldc + n0 + 4 * tn;
    if (n0 + 4 * tn + 4 <= N) {
      *(float4*)cp = make_float4((float)acc[r][0], (float)acc[r][1],
                                 (float)acc[r][2], (float)acc[r][3]);
    } else {
#pragma unroll
      for (int c = 0; c < 4; ++c)
        if (n0 + 4 * tn + c < N) cp[c] = (float)acc[r][c];
    }
  }
}

// ---------------- persistent BiLSTM v6: f32 h-exchange + phase-split stage
// v5 post-mortem: per-step 8.1 µs ≈ LDS b128 h-reads (~2 µs) + f64 FMA (~1.3) +
// 102 KB f64 stage (~1.3) + sync/straggler (~2+). v6:
// (a) h exchanged as f32 (global AND LDS). h is f32 in the reference; (double)(float)h
//     at use is exact, so the only change is f32 rounding of h once per step (~1e-8 rel),
//     far below the reference's own f32 noise. Halves stage bytes and h LDS reads;
//     the float2 inner read tiles 32 banks exactly per kp group -> 4 cy/issue.
// (b) phase-split stage at k=192 (12+13 float2/thread, exact 256-thread tiles): issue all
//     25 global loads, write LDS phase 1, barrier, compute kk<48 while phase-2 loads land
//     (phase-2 LDS writes touch a disjoint range - no barrier needed to start), barrier,
//     compute kk>=48. Hides phase-2 stage latency under phase-1 compute.
// (c) only wave 0 polls (50 lanes x 2 flags): 4x less load traffic on the flag lines ->
//     less MALL contention against the publish stores.
// Publish protocol unchanged from v5 (flag = #publishes; WAR-safety argument identical).
__global__ __launch_bounds__(256, 1) void k_lstm3(const float* __restrict__ xwt,   // [2][128][32][1600] f32
                                                  const float* __restrict__ whh_f, // [1600][400]
                                                  const float* __restrict__ whh_b,
                                                  const int* __restrict__ word_idxs,
                                                  float* __restrict__ hbuf,        // [2][2][400][32] f32
                                                  unsigned* __restrict__ flags,    // [2][128] u32
                                                  float* __restrict__ enc) {
  __shared__ __align__(16) double Wvd[4 * 400 * 4];   // [u][k][g] f64, 51,200 B
  __shared__ __align__(16) float  Shf[12800];          // h tile [k 0..399][b 0..31] f32, 51,200 B
  int bid = blockIdx.x;
  int d = bid / 100, slice = bid - d * 100;
  const float* whh = d ? whh_b : whh_f;
  const float* xwd = xwt + (size_t)d * SEQL * 32 * G4;
  unsigned* flg = flags + (size_t)d * 128;
  int t = threadIdx.x;

  // one-time: stage Whh rows for our 4 units x 4 gates into LDS as f64 [u][k][g]
  for (int pp = 0; pp < 16; ++pp) {
    int u = pp >> 2, g = pp & 3;
    const float* src = whh + (size_t)(g * 400 + slice * 4 + u) * 400;
    for (int k = t; k < 400; k += 256) Wvd[((size_t)u * 400 + k) * 4 + g] = (double)src[k];
  }

  int su = t >> 6;          // wave id = unit index within slice (0..3)
  int lane = t & 63;
  int kp = lane >> 4;       // k-phase (0..3) — high lane bits: conflict-free Shf reads
  int p  = lane & 15;       // batch-pair index (0..15)
  int sb2 = 2 * p;
  int kglob = slice * 4 + su;
  int cb = sb2 + kp;        // this thread's batch column (valid for kp<2)
  double cst = 0.0;

  if (kp < 2)
    astoref(&hbuf[((size_t)1 * 2 + d) * 12800 + (size_t)kglob * 32 + cb], 0.f);
  __syncthreads();                        // drain vmcnt (h init visible)
  if (t == 0) afstore(&flg[slice], 1u);   // publish #1 (initial h)

  for (int s = 0; s < SEQL; ++s) {
    int l = d ? (SEQL - 1 - s) : s;
    int rp = (s + 1) & 1, wp = s & 1;
    const float2* hr2 = (const float2*)(hbuf + ((size_t)rp * 2 + d) * 12800);
    float* hwb = hbuf + ((size_t)wp * 2 + d) * 12800;
    unsigned need = (unsigned)(s + 1);

    // prefetch xw gates + mask for (unit su, batch cb) — consumed at step end (latency hidden)
    float xw0 = 0.f, xw1 = 0.f, xw2 = 0.f, xw3 = 0.f;
    bool m = false;
    if (kp < 2) {
      const float* xp = xwd + ((size_t)l * 32 + cb) * G4 + kglob;
      xw0 = xp[0]; xw1 = xp[400]; xw2 = xp[800]; xw3 = xp[1200];
      m = word_idxs[cb * SEQL + l] > 0;
    }

    // wave 0 polls all 100 producer flags (50 lanes x 2); others wait at the barrier
    if (su == 0) {
      bool mine = lane < 50;
      const unsigned* fpa = flg + lane;
      const unsigned* fpb = flg + 50 + lane;
      while (true) {
        unsigned va = mine ? afload(fpa) : 0xFFFFFFFFu;
        unsigned vb = mine ? afload(fpb) : 0xFFFFFFFFu;
        if (__ballot((va < need) || (vb < need)) == 0ull) break;
        __builtin_amdgcn_s_sleep(1);
      }
    }
    __syncthreads();   // all 100 flags >= s+1; prior-step Shf consumption done

    // stage h tile (400x32 f32 = 6400 float2): issue ALL loads, write phase 1 (f2 idx<3072)
    float2 r[25];
#pragma unroll
    for (int j = 0; j < 25; ++j) r[j] = aload2f(&hr2[t + 256 * j]);
    float2* Shf2 = (float2*)Shf;
#pragma unroll
    for (int j = 0; j < 12; ++j) Shf2[t + 256 * j] = r[j];
    __syncthreads();   // phase-1 tile (k<192) ready

    double acc[8];
#pragma unroll
    for (int z = 0; z < 8; ++z) acc[z] = 0.0;
#pragma unroll 4
    for (int kk = 0; kk < 48; ++kk) {
      int klocal = 4 * kk + kp;
      float2 hp = *(const float2*)&Shf[(size_t)klocal * 32 + sb2];
      const double2* wrow = (const double2*)&Wvd[((size_t)su * 400 + klocal) * 4];
      double2 w01 = wrow[0];   // gates i,f
      double2 w23 = wrow[1];   // gates g,o
      double hx = (double)hp.x, hy = (double)hp.y;
      acc[0] = fma(w01.x, hx, acc[0]);
      acc[1] = fma(w01.x, hy, acc[1]);
      acc[2] = fma(w01.y, hx, acc[2]);
      acc[3] = fma(w01.y, hy, acc[3]);
      acc[4] = fma(w23.x, hx, acc[4]);
      acc[5] = fma(w23.x, hy, acc[5]);
      acc[6] = fma(w23.y, hx, acc[6]);
      acc[7] = fma(w23.y, hy, acc[7]);
    }

    // write phase-2 tile (disjoint LDS range; loads landed during phase-1 compute)
#pragma unroll
    for (int j = 12; j < 25; ++j) Shf2[t + 256 * j] = r[j];
    __syncthreads();   // phase-2 tile (k>=192) ready

#pragma unroll 4
    for (int kk = 48; kk < 100; ++kk) {
      int klocal = 4 * kk + kp;
      float2 hp = *(const float2*)&Shf[(size_t)klocal * 32 + sb2];
      const double2* wrow = (const double2*)&Wvd[((size_t)su * 400 + klocal) * 4];
      double2 w01 = wrow[0];
      double2 w23 = wrow[1];
      double hx = (double)hp.x, hy = (double)hp.y;
      acc[0] = fma(w01.x, hx, acc[0]);
      acc[1] = fma(w01.x, hy, acc[1]);
      acc[2] = fma(w01.y, hx, acc[2]);
      acc[3] = fma(w01.y, hy, acc[3]);
      acc[4] = fma(w23.x, hx, acc[4]);
      acc[5] = fma(w23.x, hy, acc[5]);
      acc[6] = fma(w23.y, hx, acc[6]);
      acc[7] = fma(w23.y, hy, acc[7]);
    }
    // reduce the 4-way k-split across kp groups (lane bits 4,5)
#pragma unroll
    for (int z = 0; z < 8; ++z) {
      acc[z] += __shfl_xor(acc[z], 16);
      acc[z] += __shfl_xor(acc[z], 32);
    }

    if (kp < 2) {
      double gi = acc[0 + kp] + (double)xw0;
      double gf = acc[2 + kp] + (double)xw1;
      double gg = acc[4 + kp] + (double)xw2;
      double go = acc[6 + kp] + (double)xw3;
      double si = (double)(1.f / (1.f + expf(-(float)gi)));
      double sf = (double)(1.f / (1.f + expf(-(float)gf)));
      double so = (double)(1.f / (1.f + expf(-(float)go)));
      double cn = sf * cst + si * (double)tanhf((float)gg);
      double hn = so * (double)tanhf((float)cn);
      float holdv = Shf[(size_t)kglob * 32 + cb];   // own published h from step s-1 (exact f32)
      float hv = m ? (float)hn : holdv;
      cst = m ? cn : cst;
      astoref(&hwb[(size_t)kglob * 32 + cb], hv);
      enc[((size_t)cb * SEQL + l) * 800 + d * 400 + kglob] = m ? (float)hn : 0.f;
    }
    __syncthreads();                          // drain vmcnt: h stores visible
    if (t == 0) afstore(&flg[slice], (unsigned)(s + 2));   // publish
  }
}

// ---------------- stage 2: score + argmax per (b,x), emits sort keys ----------------
__global__ __launch_bounds__(128) void k_stage2(const float* __restrict__ U,
                                                const float* __restrict__ y1T,
                                                const int* __restrict__ labels,
                                                unsigned long long* __restrict__ keys) {
  __shared__ double Ur[4644];
  int bx = blockIdx.x;
  int b = bx >> 7, x = bx & 127;
  const float* Urow = U + (size_t)bx * 4644;
  for (int i = threadIdx.x; i < 4644; i += 128) Ur[i] = (double)Urow[i];
  __syncthreads();
  int y = threadIdx.x;
  double acc[9];
#pragma unroll
  for (int o = 0; o < 9; ++o) acc[o] = 0.0;
  const float* yb = y1T + (size_t)b * 513 * 128 + y;
  for (int j = 0; j < 513; ++j) {
    double yv = (double)yb[(size_t)j * 128];
#pragma unroll
    for (int o = 0; o < 9; ++o) acc[o] = fma(Ur[o * 516 + j], yv, acc[o]);
  }
  double best = acc[0];
  int bi = 0;
#pragma unroll
  for (int o = 1; o < 9; ++o) {
    if (acc[o] > best) { best = acc[o]; bi = o; }
  }
  int fi = x * 128 + y;
  int lab = labels[(size_t)bx * 128 + y];
  bool valid = (bi != 1) && (lab > 0);
  unsigned long long key;
  if (valid) {
    unsigned long long u = (unsigned long long)__double_as_longlong(best);
    unsigned long long mm = (u >> 63) ? ~u : (u | 0x8000000000000000ull);
    unsigned long long dm = ~mm;
    key = (dm & ~0x3FFFFull) | ((unsigned long long)(unsigned)fi << 4) |
          (unsigned long long)(unsigned)bi;
  } else {
    key = ~0ull;
  }
  keys[(size_t)b * 16384 + fi] = key;
}

// ---------------- decode phase 1: sort 2048-key chunks (8 per sentence, 256 blocks total)
// Also initializes the output to NON_ENTITY=1 (coalesced, spread across all blocks).
__global__ __launch_bounds__(256) void k_sortchunks(unsigned long long* __restrict__ keysg,
                                                    int* __restrict__ outp) {
  __shared__ unsigned long long s[2048];
  int c = blockIdx.x, b = blockIdx.y;
  unsigned long long* kg = keysg + (size_t)b * 16384 + (size_t)c * 2048;
  int* ob = outp + (size_t)b * 16384 + (size_t)c * 2048;
  int t = threadIdx.x;
  for (int i = t; i < 2048; i += 256) s[i] = kg[i];
  for (int i = t; i < 2048; i += 256) ob[i] = 1;
  __syncthreads();
  for (int k = 2; k <= 2048; k <<= 1) {
    for (int j = k >> 1; j > 0; j >>= 1) {
#pragma unroll
      for (int p = 0; p < 4; ++p) {
        int ii = p * 256 + t;                       // compare index 0..1023
        int i = ((ii & ~(j - 1)) << 1) | (ii & (j - 1));
        int ix = i | j;
        bool up = ((i & k) == 0);
        unsigned long long a = s[i], bb = s[ix];
        if (up ? (a > bb) : (a < bb)) { s[i] = bb; s[ix] = a; }
      }
      __syncthreads();
    }
  }
  for (int i = t; i < 2048; i += 256) kg[i] = s[i];
}

// ---------------- decode phase 2: per-sentence merge 8x2048 -> 16384 (ascending) ----------------
__global__ __launch_bounds__(1024) void k_merge8(unsigned long long* __restrict__ keysg) {
  extern __shared__ unsigned long long m[];   // 8192 u64 = 64 KB
  int b = blockIdx.x;
  int t = threadIdx.x;
  unsigned long long* kg = keysg + (size_t)b * 16384;

  // Round A: merge pairs of 2048-runs -> 4096-runs (two pairs per pass, both ascending)
  for (int pass = 0; pass < 2; ++pass) {
    unsigned long long* base = kg + (size_t)pass * 8192;
    for (int i = t; i < 2048; i += 1024) {
      m[i]        = base[i];                    // run0 fwd
      m[2048 + i] = base[2048 + 2047 - i];      // run1 rev -> bitonic block 0
      m[4096 + i] = base[4096 + i];             // run2 fwd
      m[6144 + i] = base[6144 + 2047 - i];      // run3 rev -> bitonic block 1
    }
    __syncthreads();
    for (int j = 2048; j > 0; j >>= 1) {
#pragma unroll
      for (int p = 0; p < 4; ++p) {
        int ii = p * 1024 + t;                  // compare idx 0..4095 over 8192 elems
        int i = ((ii & ~(j - 1)) << 1) | (ii & (j - 1));
        int ix = i | j;
        unsigned long long a = m[i], c = m[ix];
        if (a > c) { m[i] = c; m[ix] = a; }     // ascending in both 4096-blocks
      }
      __syncthreads();
    }
    for (int i = t; i < 8192; i += 1024) base[i] = m[i];
    __syncthreads();
  }

  // Round B: merge 4096+4096 -> 8192; half 0 ascending, half 1 DESCENDING (sets up round C)
  for (int pass = 0; pass < 2; ++pass) {
    unsigned long long* base = kg + (size_t)pass * 8192;
    for (int i = t; i < 4096; i += 1024) {
      m[i]        = base[i];                    // fwd
      m[4096 + i] = base[4096 + 4095 - i];      // rev -> bitonic 8192
    }
    __syncthreads();
    bool desc = (pass == 1);
    for (int j = 4096; j > 0; j >>= 1) {
#pragma unroll
      for (int p = 0; p < 4; ++p) {
        int ii = p * 1024 + t;                  // compare idx 0..4095
        int i = ((ii & ~(j - 1)) << 1) | (ii & (j - 1));
        int ix = i | j;
        unsigned long long a = m[i], c = m[ix];
        if (desc ? (a < c) : (a > c)) { m[i] = c; m[ix] = a; }
      }
      __syncthreads();
    }
    for (int i = t; i < 8192; i += 1024) base[i] = m[i];
    __syncthreads();
  }

  // Round C: asc ++ desc = bitonic 16384. Global stage j=8192, then two 8192 LDS asc merges.
  for (int i = t; i < 8192; i += 1024) {
    unsigned long long a = kg[i], c = kg[i + 8192];
    if (a > c) { kg[i] = c; kg[i + 8192] = a; }
  }
  __syncthreads();
  for (int half = 0; half < 2; ++half) {
    unsigned long long* base = kg + (size_t)half * 8192;
    for (int i = t; i < 8192; i += 1024) m[i] = base[i];
    __syncthreads();
    for (int j = 4096; j > 0; j >>= 1) {
#pragma unroll
      for (int p = 0; p < 4; ++p) {
        int ii = p * 1024 + t;
        int i = ((ii & ~(j - 1)) << 1) | (ii & (j - 1));
        int ix = i | j;
        unsigned long long a = m[i], c = m[ix];
        if (a > c) { m[i] = c; m[ix] = a; }
      }
      __syncthreads();
    }
    for (int i = t; i < 8192; i += 1024) base[i] = m[i];
    __syncthreads();
  }
}

// ---------------- decode helpers ----------------
__device__ __forceinline__ void rangemask(int i, int j,
                                          unsigned long long& r0, unsigned long long& r1) {
  if (i > j) { r0 = 0ull; r1 = 0ull; return; }
  unsigned long long u0, u1;
  if (j >= 64) { u0 = ~0ull; u1 = (j >= 127) ? ~0ull : ((1ull << (j - 63)) - 1ull); }
  else         { u0 = (j == 63) ? ~0ull : ((1ull << (j + 1)) - 1ull); u1 = 0ull; }
  unsigned long long f0, f1;
  if (i >= 64) { f0 = 0ull; f1 = (~0ull) << (i - 64); }
  else         { f0 = (~0ull) << i; f1 = ~0ull; }
  r0 = u0 & f0; r1 = u1 & f1;
}

// ---------------- decode phase 3: batched greedy NMS scan (decision-equivalent to serial)
__global__ __launch_bounds__(64) void k_scan(const unsigned long long* __restrict__ keysg,
                                             int* __restrict__ outp) {
  int b = blockIdx.x;
  int lane = threadIdx.x;
  const unsigned long long* kg = keysg + (size_t)b * 16384;
  int* ob = outp + (size_t)b * 16384;
  unsigned long long s0 = 0, s1 = 0, in0 = 0, in1 = 0;

  for (int base = 0; base < 16384; base += 64) {
    unsigned long long key = kg[base + lane];
    bool valid = (key != ~0ull);
    if (__ballot(valid) == 0ull) break;          // keys ascending: rest invalid too
    int fi = (int)((key >> 4) & 0x3FFFull);
    int ci = fi >> 7, cj = fi & 127, ca = (int)(key & 15ull);
    bool isR = (ci <= cj);
    unsigned long long r0, r1; rangemask(ci, cj, r0, r1);
    unsigned long long rangeB = __ballot(isR);
    unsigned long long unp = __ballot(valid);

    while (unp) {
      bool insb = (((ci < 64) ? (in0 >> ci) : (in1 >> (ci - 64))) & 1ull) != 0;
      bool ovl = ((r0 & s0) | (r1 & s1)) != 0ull;
      bool myc = insb || (isR && ovl);
      unsigned long long confl = __ballot(myc);
      unp &= ~confl;                              // monotone -> permanent reject
      if (!unp) break;
      unsigned long long er = unp & rangeB;
      if (er == 0ull) {
        // all remaining are non-conflicting points: accept all, update starts, done
        if ((unp >> lane) & 1ull) ob[fi] = ca;
        unsigned long long c0 = 0, c1 = 0;
        if ((unp >> lane) & 1ull) { if (ci < 64) c0 = 1ull << ci; else c1 = 1ull << (ci - 64); }
#pragma unroll
        for (int off = 32; off; off >>= 1) { c0 |= __shfl_xor(c0, off); c1 |= __shfl_xor(c1, off); }
        s0 |= c0; s1 |= c1;
        break;
      }
      int r = __ffsll((long long)er) - 1;
      unsigned long long below = (r == 0) ? 0ull : ((1ull << r) - 1ull);
      unsigned long long pb = unp & below;        // all points (earlier ranges rejected/processed)
      if (pb) {
        if ((pb >> lane) & 1ull) ob[fi] = ca;
        unsigned long long c0 = 0, c1 = 0;
        if ((pb >> lane) & 1ull) { if (ci < 64) c0 = 1ull << ci; else c1 = 1ull << (ci - 64); }
#pragma unroll
        for (int off = 32; off; off >>= 1) { c0 |= __shfl_xor(c0, off); c1 |= __shfl_xor(c1, off); }
        s0 |= c0; s1 |= c1;
        unp &= ~pb;
      }
      // decide range candidate r against the updated starts
      int wi = __shfl(ci, r), wj = __shfl(cj, r), wa = __shfl(ca, r), wfi = __shfl(fi, r);
      unsigned long long rr0, rr1; rangemask(wi, wj, rr0, rr1);
      bool rin = (((wi < 64) ? (in0 >> wi) : (in1 >> (wi - 64))) & 1ull) != 0;
      bool rovl = ((rr0 & s0) | (rr1 & s1)) != 0ull;
      if (!(rin || rovl)) {
        if (lane == r) ob[wfi] = wa;
        if (wi < 64) s0 |= 1ull << wi; else s1 |= 1ull << (wi - 64);
        in0 |= rr0; in1 |= rr1;
      }
      unp &= ~(1ull << r);
    }
  }
}

extern "C" void kernel_launch(void* const* d_in, const int* in_sizes, int n_in,
                              void* d_out, int out_size, void* d_ws, size_t ws_size,
                              hipStream_t stream) {
  const int*   word_idxs = (const int*)d_in[0];
  const int*   labels    = (const int*)d_in[1];
  const float* word_emb  = (const float*)d_in[2];
  const float* Wih_f = (const float*)d_in[3];
  const float* Whh_f = (const float*)d_in[4];
  const float* bih_f = (const float*)d_in[5];
  const float* bhh_f = (const float*)d_in[6];
  const float* Wih_b = (const float*)d_in[7];
  const float* Whh_b = (const float*)d_in[8];
  const float* bih_b = (const float*)d_in[9];
  const float* bhh_b = (const float*)d_in[10];
  const float* W_start = (const float*)d_in[11];
  const float* b_start = (const float*)d_in[12];
  const float* W_end   = (const float*)d_in[13];
  const float* b_end   = (const float*)d_in[14];
  const float* W_bi    = (const float*)d_in[15];

  char* ws = (char*)d_ws;
  float* x    = (float*)(ws + OFF_X);
  float* hbuf = (float*)(ws + OFF_HBUF);
  unsigned* flags = (unsigned*)(ws + OFF_FLG);
  float* XWt  = (float*)(ws + OFF_XW);
  float* he   = (float*)(ws + OFF_HE);
  float* enc  = (float*)(ws + OFF_ENC);
  float* U    = (float*)(ws + OFF_U);
  float* x1   = (float*)(ws + OFF_X1);
  float* y1T  = (float*)(ws + OFF_Y1T);
  float* Wbp  = (float*)(ws + OFF_WBP);
  unsigned long long* keys = (unsigned long long*)(ws + OFF_KEYS);
  int* outp = (int*)d_out;

  // 1. embedding gather
  k_gather<<<4096, 256, 0, stream>>>(word_idxs, word_emb, x);
  // 2. input-gate GEMMs, bias folded, stored coalesced as XWt[d][l][b][1600]
  dim3 g2(64, 25);
  k_gemm_nt<<<g2, 256, 0, stream>>>(x, EMBD, Wih_f, EMBD, bih_f, bhh_f,
                                    XWt, 0, 4096, G4, EMBD, 2);
  k_gemm_nt<<<g2, 256, 0, stream>>>(x, EMBD, Wih_b, EMBD, bih_b, bhh_b,
                                    XWt + (size_t)SEQL * 32 * G4, 0, 4096, G4, EMBD, 2);
  // 3. flags zero (x region now dead), then persistent LSTM (flag-synced)
  hipMemsetAsync(ws + OFF_FLG, 0, 4096, stream);
  k_lstm3<<<NBLK, 256, 0, stream>>>(XWt, Whh_f, Whh_b, word_idxs, hbuf, flags, enc);
  // 4. projections: x1 (coalesced) and he (coalesced) -> y1T via LDS transpose
  dim3 g4(64, 8);
  k_gemm_nt<<<g4, 256, 0, stream>>>(enc, 800, W_start, 800, b_start, nullptr,
                                    x1, 516, 4096, FF, 800, 0);
  k_gemm_nt<<<g4, 256, 0, stream>>>(enc, 800, W_end, 800, b_end, nullptr,
                                    he, 512, 4096, FF, 800, 0);
  dim3 gt(16, 4, 32);
  k_y1t<<<gt, 256, 0, stream>>>(he, y1T);
  k_ones<<<32, 256, 0, stream>>>(x1, y1T);
  // 5. biaffine stage 1: U[b,x][o][j] = sum_i x1[b,x,i] W[o,i,j]
  k_wbpad<<<(9 * 513 * 516 + 255) / 256, 256, 0, stream>>>(W_bi, Wbp);
  dim3 g5(64, 9, 9);
  k_gemm_nn<<<g5, 256, 0, stream>>>(x1, 516, Wbp, 516, (size_t)513 * 516,
                                    U, 4644, 4096, 513, 513);
  // 6. stage 2 + argmax + key build
  k_stage2<<<4096, 128, 0, stream>>>(U, y1T, labels, keys);
  // 7. decode: chunk sort (full GPU) -> per-sentence merge -> batched NMS scan
  dim3 gs(8, 32);
  k_sortchunks<<<gs, 256, 0, stream>>>(keys, outp);
  k_merge8<<<32, 1024, 65536, stream>>>(keys);
  k_scan<<<32, 64, 0, stream>>>(keys, outp);
}